// Round 1
// baseline (4005.815 us; speedup 1.0000x reference)
//
#include <hip/hip_runtime.h>
#include <math.h>

// ---------------------------------------------------------------------------
// ImplicitFlowDecoder fused kernel — fp32 correctness-first baseline.
// Each block: 32 consecutive full-res pixels (one row segment).
// Activations ping-pong between two LDS buffers; weights stream from global
// (L2-resident, ~1 MB total). No workspace needed.
// ---------------------------------------------------------------------------

constexpr int W8 = 64, H8 = 48;          // s8 feature grid
constexpr int W16 = 32, H16 = 24;        // s16 feature grid
constexpr int WF = 512, HF = 384;        // full-res query grid
constexpr int HWs8 = W8 * H8;            // 3072
constexpr int HWs16 = W16 * H16;         // 768
constexpr int Mp = 32;                   // points per block
constexpr int SA = 264;                  // LDS row stride bufA (pad from 260)
constexpr int SB = 264;                  // LDS row stride bufB
constexpr int NTH = 256;
constexpr int BLOCKS_PER_ROW = WF / Mp;               // 16
constexpr int BLOCKS_PER_BATCH = HF * BLOCKS_PER_ROW; // 6144

struct Params {
  const float* feat_s8; const float* feat1_s8; const float* feat_s16;
  const float* ctx_s8;  const float* coarse;
  const float* Wc; const float* bc; const float* g1;
  const float* W1; const float* b1; const float* W2; const float* b2;
  const float* Wp; const float* bp; const float* g2;
  const float* W3; const float* b3; const float* W4; const float* b4;
  const float* h0w; const float* h0b; const float* h1w; const float* h1b;
  const float* h2w; const float* h2b; const float* h3w; const float* h3b;
  float* out;
};

__device__ __forceinline__ void bilin_setup(float g, int S, int& i0, int& i1, float& w) {
  float s = (g + 1.0f) * (0.5f * S) - 0.5f;
  float f = floorf(s);
  w = s - f;                       // weight from UNCLIPPED floor (matches ref)
  int a = (int)f;
  i0 = min(max(a, 0), S - 1);
  i1 = min(max(a + 1, 0), S - 1);
}

#define EP_PLAIN 0
#define EP_GELU  1
#define EP_RELU  2
#define EP_GATED 3

__device__ __forceinline__ float apply_ep(int ep, float x) {
  if (ep == EP_GELU) return 0.5f * x * (1.0f + erff(x * 0.70710678118654752f));
  if (ep == EP_RELU) return fmaxf(x, 0.0f);
  return x;
}

// GEMM over a 32-point tile. actIn [32 x K] in LDS, W [K x NOUT] row-major in
// global, out [32 x NOUT] in LDS. 4 groups x 8 points/thread x 2 col-chunks.
// Internal __syncthreads() between read phase and write phase makes
// in-place (actIn == actOut) single-pass layers (NOUT<=128) safe.
__device__ void gemm_tile(const float* __restrict__ W, const float* __restrict__ bias,
                          const float* actIn, int sIn, int K,
                          float* actOut, int sOut, int NOUT,
                          int ep, const float* __restrict__ gate,
                          const float* addSrc, int sAdd)
{
  const int t = threadIdx.x;
  const int lane = t & 63;
  const int grp = t >> 6;        // 0..3
  const int i0 = grp * 8;        // 8 points per thread
  const int nch = NOUT >> 6;     // 64-wide column chunks

  for (int c0 = 0; c0 < nch; c0 += 2) {
    const int n0 = c0 * 64 + lane;
    const bool two = (c0 + 1) < nch;
    const int n1 = two ? (n0 + 64) : n0;   // safe dummy when single-chunk
    float acc0[8], acc1[8];
#pragma unroll
    for (int j = 0; j < 8; ++j) { acc0[j] = 0.0f; acc1[j] = 0.0f; }

    for (int k = 0; k < K; k += 4) {
      float4 a[8];
#pragma unroll
      for (int j = 0; j < 8; ++j)
        a[j] = *(const float4*)(actIn + (i0 + j) * sIn + k);   // wave-uniform addr -> broadcast
#pragma unroll
      for (int kk = 0; kk < 4; ++kk) {
        float w0 = W[(k + kk) * NOUT + n0];
        float w1 = W[(k + kk) * NOUT + n1];
#pragma unroll
        for (int j = 0; j < 8; ++j) {
          float av = (&a[j].x)[kk];
          acc0[j] = fmaf(av, w0, acc0[j]);
          acc1[j] = fmaf(av, w1, acc1[j]);
        }
      }
    }

    __syncthreads();   // all reads of actIn done before any writes (in-place safety)

    float b0 = bias[n0];
    float b1v = bias[n1];
    float sg0 = 0.0f, sg1 = 0.0f;
    if (ep == EP_GATED) {
      sg0 = 1.0f / (1.0f + expf(-gate[n0]));
      sg1 = 1.0f / (1.0f + expf(-gate[n1]));
    }
#pragma unroll
    for (int j = 0; j < 8; ++j) {
      int i = i0 + j;
      float x0 = acc0[j] + b0;
      float v0 = (ep == EP_GATED) ? (addSrc[i * sAdd + n0] + sg0 * x0)
                                  : apply_ep(ep, x0);
      actOut[i * sOut + n0] = v0;
      if (two) {
        float x1 = acc1[j] + b1v;
        float v1 = (ep == EP_GATED) ? (addSrc[i * sAdd + n1] + sg1 * x1)
                                    : apply_ep(ep, x1);
        actOut[i * sOut + n1] = v1;
      }
    }
  }
}

// Bilinear-sample C channels for the 32 tile points into LDS columns.
__device__ void sample_tile(const float* __restrict__ fm, int C, int HW,
                            const int* offs, const float* wxA, const float* wyA,
                            float* outBuf, int sOut, int colOff)
{
  for (int item = threadIdx.x; item < Mp * C; item += NTH) {
    int i = item & (Mp - 1);
    int c = item >> 5;
    const float* p = fm + c * HW;
    float v00 = p[offs[0 * Mp + i]];
    float v01 = p[offs[1 * Mp + i]];
    float v10 = p[offs[2 * Mp + i]];
    float v11 = p[offs[3 * Mp + i]];
    float wx = wxA[i], wy = wyA[i];
    float vx0 = v00 + wx * (v01 - v00);
    float vx1 = v10 + wx * (v11 - v10);
    outBuf[i * sOut + colOff + c] = vx0 + wy * (vx1 - vx0);
  }
}

__global__ __launch_bounds__(256, 2)
void ifd_kernel(Params p)
{
  __shared__ __align__(16) float bufA[Mp * SA];
  __shared__ __align__(16) float bufB[Mp * SB];
  __shared__ int offs8[4 * Mp];
  __shared__ int offs16[4 * Mp];
  __shared__ int offsW[4 * Mp];
  __shared__ float w8x[Mp], w8y[Mp], w16x[Mp], w16y[Mp], wWx[Mp], wWy[Mp];
  __shared__ float caxA[Mp], cayA[Mp], gxA[Mp], gyA[Mp];

  const int blk = blockIdx.x;
  const int bb = blk / BLOCKS_PER_BATCH;
  const int r = blk % BLOCKS_PER_BATCH;
  const int y = r >> 4;            // r / BLOCKS_PER_ROW
  const int xb = (r & 15) * Mp;

  const int t = threadIdx.x;
  if (t < Mp) {
    const int i = t;
    const int x = xb + i;
    const float lim = 1.0f - 1e-6f;
    float gx = (x + 0.5f) * (2.0f / WF) - 1.0f;
    float gy = (y + 0.5f) * (2.0f / HF) - 1.0f;
    gx = fminf(fmaxf(gx, -lim), lim);
    gy = fminf(fmaxf(gy, -lim), lim);
    gxA[i] = gx; gyA[i] = gy;

    int x0, x1, y0, y1; float wx, wy;
    bilin_setup(gx, W8, x0, x1, wx);
    bilin_setup(gy, H8, y0, y1, wy);
    int o00 = y0 * W8 + x0, o01 = y0 * W8 + x1;
    int o10 = y1 * W8 + x0, o11 = y1 * W8 + x1;
    offs8[0 * Mp + i] = o00; offs8[1 * Mp + i] = o01;
    offs8[2 * Mp + i] = o10; offs8[3 * Mp + i] = o11;
    w8x[i] = wx; w8y[i] = wy;

    int a0, a1, b0i, b1i; float vx, vy;
    bilin_setup(gx, W16, a0, a1, vx);
    bilin_setup(gy, H16, b0i, b1i, vy);
    offs16[0 * Mp + i] = b0i * W16 + a0; offs16[1 * Mp + i] = b0i * W16 + a1;
    offs16[2 * Mp + i] = b1i * W16 + a0; offs16[3 * Mp + i] = b1i * W16 + a1;
    w16x[i] = vx; w16y[i] = vy;

    // coarse flow (2ch on s8 grid), scale = (WF/W8, HF/H8) = (8,8)
    const float* cf = p.coarse + bb * 2 * HWs8;
    float c00 = cf[o00], c01 = cf[o01], c10 = cf[o10], c11 = cf[o11];
    float cx0 = c00 + wx * (c01 - c00), cx1 = c10 + wx * (c11 - c10);
    float cfx = cx0 + wy * (cx1 - cx0);
    const float* cf2 = cf + HWs8;
    c00 = cf2[o00]; c01 = cf2[o01]; c10 = cf2[o10]; c11 = cf2[o11];
    cx0 = c00 + wx * (c01 - c00); cx1 = c10 + wx * (c11 - c10);
    float cfy = cx0 + wy * (cx1 - cx0);
    float cax = cfx * 8.0f, cay = cfy * 8.0f;
    caxA[i] = cax; cayA[i] = cay;

    // warp coords, clipped, then s8-grid bilinear params for feat1_s8
    float wxn = gx + cax * (2.0f / WF);
    float wyn = gy + cay * (2.0f / HF);
    wxn = fminf(fmaxf(wxn, -lim), lim);
    wyn = fminf(fmaxf(wyn, -lim), lim);
    int u0, u1, v0, v1; float uw, vw;
    bilin_setup(wxn, W8, u0, u1, uw);
    bilin_setup(wyn, H8, v0, v1, vw);
    offsW[0 * Mp + i] = v0 * W8 + u0; offsW[1 * Mp + i] = v0 * W8 + u1;
    offsW[2 * Mp + i] = v1 * W8 + u0; offsW[3 * Mp + i] = v1 * W8 + u1;
    wWx[i] = uw; wWy[i] = vw;
  }
  __syncthreads();

  // fctx -> bufB[:,0:64); f8 -> bufA[:,0:128)
  sample_tile(p.ctx_s8 + bb * 64 * HWs8, 64, HWs8, offs8, w8x, w8y, bufB, SB, 0);
  sample_tile(p.feat_s8 + bb * 128 * HWs8, 128, HWs8, offs8, w8x, w8y, bufA, SA, 0);
  __syncthreads();

  // h1 = f8 + sig(g1) * (fctx @ Wc + bc)           (in bufA, in-place add)
  gemm_tile(p.Wc, p.bc, bufB, SB, 64, bufA, SA, 128, EP_GATED, p.g1, bufA, SA);
  __syncthreads();
  // m1 = gelu(h1 @ W1 + b1)                        bufA -> bufB[0:256)
  gemm_tile(p.W1, p.b1, bufA, SA, 128, bufB, SB, 256, EP_GELU, nullptr, nullptr, 0);
  __syncthreads();
  // h2 = m1 @ W2 + b2                              bufB -> bufA[0:128)
  gemm_tile(p.W2, p.b2, bufB, SB, 256, bufA, SA, 128, EP_PLAIN, nullptr, nullptr, 0);
  __syncthreads();
  // f16 -> bufB[:,0:128)
  sample_tile(p.feat_s16 + bb * 128 * HWs16, 128, HWs16, offs16, w16x, w16y, bufB, SB, 0);
  __syncthreads();
  // h3 = f16 + sig(g2) * (h2 @ Wp + bp)            bufA -> bufA (in-place, synced)
  gemm_tile(p.Wp, p.bp, bufA, SA, 128, bufA, SA, 128, EP_GATED, p.g2, bufB, SB);
  __syncthreads();
  // m2 = gelu(h3 @ W3 + b3)                        bufA -> bufB[0:256)
  gemm_tile(p.W3, p.b3, bufA, SA, 128, bufB, SB, 256, EP_GELU, nullptr, nullptr, 0);
  __syncthreads();
  // fused = m2 @ W4 + b4                           bufB -> bufA[0:128)
  gemm_tile(p.W4, p.b4, bufB, SB, 256, bufA, SA, 128, EP_PLAIN, nullptr, nullptr, 0);
  __syncthreads();
  // f1_warped -> bufA[:,128:256); coords + coarse_norm -> bufA[:,256:260)
  sample_tile(p.feat1_s8 + bb * 128 * HWs8, 128, HWs8, offsW, wWx, wWy, bufA, SA, 128);
  if (t < Mp) {
    bufA[t * SA + 256] = gxA[t];
    bufA[t * SA + 257] = gyA[t];
    bufA[t * SA + 258] = caxA[t] * (1.0f / WF);
    bufA[t * SA + 259] = cayA[t] * (1.0f / HF);
  }
  __syncthreads();
  // flow head
  gemm_tile(p.h0w, p.h0b, bufA, SA, 260, bufB, SB, 256, EP_RELU, nullptr, nullptr, 0);
  __syncthreads();
  gemm_tile(p.h1w, p.h1b, bufB, SB, 256, bufA, SA, 128, EP_RELU, nullptr, nullptr, 0);
  __syncthreads();
  gemm_tile(p.h2w, p.h2b, bufA, SA, 128, bufB, SB, 64, EP_RELU, nullptr, nullptr, 0);
  __syncthreads();

  // final 64->2 layer + output write: flow = coarse_at_q + delta_norm * [WF,HF]
  if (t < 64) {
    int i = t & (Mp - 1);
    int comp = t >> 5;
    float acc = p.h3b[comp];
    for (int k = 0; k < 64; ++k)
      acc = fmaf(bufB[i * SB + k], p.h3w[k * 2 + comp], acc);
    float flow = (comp ? cayA[i] : caxA[i]) + acc * (comp ? (float)HF : (float)WF);
    p.out[((bb * 2 + comp) * HF + y) * WF + xb + i] = flow;
  }
}

extern "C" void kernel_launch(void* const* d_in, const int* in_sizes, int n_in,
                              void* d_out, int out_size, void* d_ws, size_t ws_size,
                              hipStream_t stream) {
  Params p;
  p.feat_s8  = (const float*)d_in[1];
  p.feat1_s8 = (const float*)d_in[2];
  p.feat_s16 = (const float*)d_in[3];
  p.ctx_s8   = (const float*)d_in[4];
  p.coarse   = (const float*)d_in[5];
  p.Wc = (const float*)d_in[6];  p.bc = (const float*)d_in[7];
  p.g1 = (const float*)d_in[8];
  p.W1 = (const float*)d_in[9];  p.b1 = (const float*)d_in[10];
  p.W2 = (const float*)d_in[11]; p.b2 = (const float*)d_in[12];
  p.Wp = (const float*)d_in[13]; p.bp = (const float*)d_in[14];
  p.g2 = (const float*)d_in[15];
  p.W3 = (const float*)d_in[16]; p.b3 = (const float*)d_in[17];
  p.W4 = (const float*)d_in[18]; p.b4 = (const float*)d_in[19];
  p.h0w = (const float*)d_in[20]; p.h0b = (const float*)d_in[21];
  p.h1w = (const float*)d_in[22]; p.h1b = (const float*)d_in[23];
  p.h2w = (const float*)d_in[24]; p.h2b = (const float*)d_in[25];
  p.h3w = (const float*)d_in[26]; p.h3b = (const float*)d_in[27];
  p.out = (float*)d_out;

  hipLaunchKernelGGL(ifd_kernel, dim3(2 * BLOCKS_PER_BATCH), dim3(NTH), 0, stream, p);
}

// Round 3
// 656.773 us; speedup vs baseline: 6.0992x; 6.0992x over previous
//
#include <hip/hip_runtime.h>
#include <math.h>

// ---------------------------------------------------------------------------
// ImplicitFlowDecoder — MFMA bf16 version (R2 fix: wave weight-base offset).
// M-dim = output features (weights as A-operand, pre-swizzled in d_ws),
// N-dim = 64 points per block (activations as B-operand from LDS).
// fp32 accumulate + fp32 epilogues; activations stored bf16 in LDS.
// ---------------------------------------------------------------------------

typedef short bf16x8 __attribute__((ext_vector_type(8)));
typedef float f32x4 __attribute__((ext_vector_type(4)));

constexpr int W8 = 64, H8 = 48, W16g = 32, H16g = 24, WF = 512, HF = 384;
constexpr int HWs8 = W8 * H8;      // 3072
constexpr int HWs16 = W16g * H16g; // 768
constexpr int MP = 64;             // points per block
constexpr int NTH = 256;
constexpr int BPR = WF / MP;                // 8 blocks per row
constexpr int NBLK = 2 * HF * BPR;          // 6144

// LDS row strides (ushort elems): multiple of 8 (16B-aligned rows) and
// ≡ 8 mod 64 so b128 row-stride lands on 2-way (free) bank aliasing.
constexpr int S64 = 72, S128 = 136, S256 = 264, S288 = 296;

// swizzled bf16 weight offsets in d_ws (elems)
constexpr int OFF_WC = 0;
constexpr int OFF_W1 = 8192;
constexpr int OFF_W2 = 40960;
constexpr int OFF_WP = 73728;
constexpr int OFF_W3 = 90112;
constexpr int OFF_W4 = 122880;
constexpr int OFF_H0 = 155648;   // K padded 260->288
constexpr int OFF_H1 = 229376;
constexpr int OFF_H2 = 262144;
constexpr int SWZ_TOTAL = 270336;

__device__ __forceinline__ unsigned short f2bf(float f) {
  union { float f; unsigned u; } v; v.f = f;
  unsigned r = (v.u + 0x7fffu + ((v.u >> 16) & 1u)) >> 16;
  return (unsigned short)r;
}
__device__ __forceinline__ float bf2f(unsigned short h) {
  union { unsigned u; float f; } v; v.u = ((unsigned)h) << 16;
  return v.f;
}

// ------------------------------- prep kernel -------------------------------
struct PrepParams { const float* W[9]; unsigned short* ws; };

__global__ void prep_kernel(PrepParams pp) {
  const int K_[9]   = {64, 128, 256, 128, 128, 256, 260, 256, 128};
  const int Kp_[9]  = {64, 128, 256, 128, 128, 256, 288, 256, 128};
  const int N_[9]   = {128, 256, 128, 128, 256, 128, 256, 128, 64};
  const int OFF_[9] = {OFF_WC, OFF_W1, OFF_W2, OFF_WP, OFF_W3, OFF_W4, OFF_H0, OFF_H1, OFF_H2};
  for (int e = blockIdx.x * blockDim.x + threadIdx.x; e < SWZ_TOTAL;
       e += gridDim.x * blockDim.x) {
    int L = 0;
#pragma unroll
    for (int i = 1; i < 9; ++i) if (e >= OFF_[i]) L = i;
    int q = e - OFF_[L];
    int j = q & 7;
    int l = (q >> 3) & 63;
    int r = q >> 9;                 // mt * nks + ks
    int nks = Kp_[L] >> 5;
    int ks = r % nks;
    int mt = r / nks;
    int n = mt * 16 + (l & 15);
    int k = ks * 32 + ((l >> 4) << 3) + j;
    float v = (k < K_[L]) ? pp.W[L][k * N_[L] + n] : 0.0f;
    pp.ws[e] = f2bf(v);
  }
}

// ------------------------------ main kernel --------------------------------
struct Params {
  const float* feat_s8; const float* feat1_s8; const float* feat_s16;
  const float* ctx_s8;  const float* coarse;
  const float* bc; const float* g1; const float* b1; const float* b2;
  const float* bp; const float* g2; const float* b3; const float* b4;
  const float* h0b; const float* h1b; const float* h2b;
  const float* h3w; const float* h3b;
  const unsigned short* ws;
  float* out;
};

__device__ __forceinline__ void bilin_setup(float g, int S, int& i0, int& i1, float& w) {
  float s = (g + 1.0f) * (0.5f * S) - 0.5f;
  float f = floorf(s);
  w = s - f;
  int a = (int)f;
  i0 = min(max(a, 0), S - 1);
  i1 = min(max(a + 1, 0), S - 1);
}

// EP: 0=plain, 1=gelu(exact erf), 2=relu, 3=gated residual
template<int MT_W, int EP>
__device__ __forceinline__ void mfma_layer(
    const unsigned short* __restrict__ Wsw,
    const float* __restrict__ bias,
    const unsigned short* actIn, int sIn, int K,
    unsigned short* actOut, int sOut,
    const float* __restrict__ gate,
    const unsigned short* res, int sRes)
{
  const int t = threadIdx.x;
  const int l = t & 63;
  const int wv = t >> 6;
  const int nks = K >> 5;
  const int mt0 = wv * MT_W;

  f32x4 acc[MT_W][4];
#pragma unroll
  for (int m = 0; m < MT_W; ++m)
#pragma unroll
    for (int p = 0; p < 4; ++p)
#pragma unroll
      for (int r = 0; r < 4; ++r) acc[m][p][r] = 0.0f;

  const unsigned short* bbase = actIn + (l & 15) * sIn + ((l >> 4) << 3);
  // fragment (mt, ks) lives at (mt*nks + ks)*512 elems; wave base = mt0*nks*512
  const unsigned short* abase = Wsw + ((size_t)mt0 * nks * 512 + l * 8);

  for (int ks = 0; ks < nks; ++ks) {
    bf16x8 B[4];
#pragma unroll
    for (int p = 0; p < 4; ++p)
      B[p] = *(const bf16x8*)(bbase + p * 16 * sIn + ks * 32);
#pragma unroll
    for (int m = 0; m < MT_W; ++m) {
      bf16x8 A = *(const bf16x8*)(abase + (m * nks + ks) * 512);
#pragma unroll
      for (int p = 0; p < 4; ++p)
        acc[m][p] = __builtin_amdgcn_mfma_f32_16x16x32_bf16(A, B[p], acc[m][p], 0, 0, 0);
    }
  }

#pragma unroll
  for (int m = 0; m < MT_W; ++m) {
    const int f0 = (mt0 + m) * 16 + ((l >> 4) << 2);
    float bia[4], gt[4];
#pragma unroll
    for (int r = 0; r < 4; ++r) bia[r] = bias[f0 + r];
    if (EP == 3) {
#pragma unroll
      for (int r = 0; r < 4; ++r) gt[r] = 1.0f / (1.0f + expf(-gate[f0 + r]));
    }
#pragma unroll
    for (int p = 0; p < 4; ++p) {
      const int pt = p * 16 + (l & 15);
      float v[4];
#pragma unroll
      for (int r = 0; r < 4; ++r) v[r] = acc[m][p][r] + bia[r];
      if (EP == 1) {
#pragma unroll
        for (int r = 0; r < 4; ++r)
          v[r] = 0.5f * v[r] * (1.0f + erff(v[r] * 0.70710678118654752440f));
      } else if (EP == 2) {
#pragma unroll
        for (int r = 0; r < 4; ++r) v[r] = fmaxf(v[r], 0.0f);
      } else if (EP == 3) {
        uint2 rv = *(const uint2*)(res + pt * sRes + f0);
        v[0] = bf2f((unsigned short)(rv.x & 0xffffu)) + gt[0] * v[0];
        v[1] = bf2f((unsigned short)(rv.x >> 16))     + gt[1] * v[1];
        v[2] = bf2f((unsigned short)(rv.y & 0xffffu)) + gt[2] * v[2];
        v[3] = bf2f((unsigned short)(rv.y >> 16))     + gt[3] * v[3];
      }
      uint2 pk;
      pk.x = (unsigned)f2bf(v[0]) | ((unsigned)f2bf(v[1]) << 16);
      pk.y = (unsigned)f2bf(v[2]) | ((unsigned)f2bf(v[3]) << 16);
      *(uint2*)(actOut + pt * sOut + f0) = pk;
    }
  }
}

// bilinear sample C channels (pairs) for 64 points into bf16 LDS columns
__device__ void sample_tile(const float* __restrict__ fm, int C, int HW,
    const short* offs, const float* wxA, const float* wyA,
    unsigned short* outBuf, int sOut, int colOff)
{
  const int items = MP * (C >> 1);
  for (int it = threadIdx.x; it < items; it += NTH) {
    int i = it & (MP - 1);
    int c2 = it >> 6;
    int o00 = offs[0 * MP + i], o01 = offs[1 * MP + i];
    int o10 = offs[2 * MP + i], o11 = offs[3 * MP + i];
    float wx = wxA[i], wy = wyA[i];
    float w00 = (1.0f - wx) * (1.0f - wy), w01 = wx * (1.0f - wy);
    float w10 = (1.0f - wx) * wy,          w11 = wx * wy;
    const float* p0 = fm + (c2 * 2) * HW;
    const float* p1 = p0 + HW;
    float r0 = p0[o00] * w00 + p0[o01] * w01 + p0[o10] * w10 + p0[o11] * w11;
    float r1 = p1[o00] * w00 + p1[o01] * w01 + p1[o10] * w10 + p1[o11] * w11;
    *(unsigned*)(outBuf + i * sOut + colOff + c2 * 2) =
        (unsigned)f2bf(r0) | ((unsigned)f2bf(r1) << 16);
  }
}

__global__ __launch_bounds__(256, 2)
void ifd_kernel(Params p)
{
  __shared__ __align__(16) unsigned short bufA[MP * S256];  // 33792 B
  __shared__ __align__(16) unsigned short bufB[MP * S288];  // 37888 B
  __shared__ short offs8[4 * MP], offs16[4 * MP], offsW[4 * MP];
  __shared__ float w8x[MP], w8y[MP], w16x[MP], w16y[MP], wWx[MP], wWy[MP];
  __shared__ float caxA[MP], cayA[MP], gxA[MP], gyA[MP];

  const int blk = blockIdx.x;
  const int bb = blk / (HF * BPR);
  const int r = blk % (HF * BPR);
  const int y = r >> 3;
  const int xb = (r & (BPR - 1)) * MP;
  const int t = threadIdx.x;

  if (t < MP) {
    const int i = t;
    const int x = xb + i;
    const float lim = 1.0f - 1e-6f;
    float gx = (x + 0.5f) * (2.0f / WF) - 1.0f;
    float gy = (y + 0.5f) * (2.0f / HF) - 1.0f;
    gx = fminf(fmaxf(gx, -lim), lim);
    gy = fminf(fmaxf(gy, -lim), lim);
    gxA[i] = gx; gyA[i] = gy;

    int x0, x1, y0, y1; float wx, wy;
    bilin_setup(gx, W8, x0, x1, wx);
    bilin_setup(gy, H8, y0, y1, wy);
    int o00 = y0 * W8 + x0, o01 = y0 * W8 + x1;
    int o10 = y1 * W8 + x0, o11 = y1 * W8 + x1;
    offs8[0 * MP + i] = (short)o00; offs8[1 * MP + i] = (short)o01;
    offs8[2 * MP + i] = (short)o10; offs8[3 * MP + i] = (short)o11;
    w8x[i] = wx; w8y[i] = wy;

    int a0, a1, b0i, b1i; float vx, vy;
    bilin_setup(gx, W16g, a0, a1, vx);
    bilin_setup(gy, H16g, b0i, b1i, vy);
    offs16[0 * MP + i] = (short)(b0i * W16g + a0);
    offs16[1 * MP + i] = (short)(b0i * W16g + a1);
    offs16[2 * MP + i] = (short)(b1i * W16g + a0);
    offs16[3 * MP + i] = (short)(b1i * W16g + a1);
    w16x[i] = vx; w16y[i] = vy;

    const float* cf = p.coarse + bb * 2 * HWs8;
    float c00 = cf[o00], c01 = cf[o01], c10 = cf[o10], c11 = cf[o11];
    float cx0 = c00 + wx * (c01 - c00), cx1 = c10 + wx * (c11 - c10);
    float cfx = cx0 + wy * (cx1 - cx0);
    const float* cf2 = cf + HWs8;
    c00 = cf2[o00]; c01 = cf2[o01]; c10 = cf2[o10]; c11 = cf2[o11];
    cx0 = c00 + wx * (c01 - c00); cx1 = c10 + wx * (c11 - c10);
    float cfy = cx0 + wy * (cx1 - cx0);
    float cax = cfx * 8.0f, cay = cfy * 8.0f;
    caxA[i] = cax; cayA[i] = cay;

    float wxn = gx + cax * (2.0f / WF);
    float wyn = gy + cay * (2.0f / HF);
    wxn = fminf(fmaxf(wxn, -lim), lim);
    wyn = fminf(fmaxf(wyn, -lim), lim);
    int u0, u1, v0, v1; float uw, vw;
    bilin_setup(wxn, W8, u0, u1, uw);
    bilin_setup(wyn, H8, v0, v1, vw);
    offsW[0 * MP + i] = (short)(v0 * W8 + u0);
    offsW[1 * MP + i] = (short)(v0 * W8 + u1);
    offsW[2 * MP + i] = (short)(v1 * W8 + u0);
    offsW[3 * MP + i] = (short)(v1 * W8 + u1);
    wWx[i] = uw; wWy[i] = vw;
  }
  __syncthreads();

  // fctx -> B(72); f8 -> A(136)
  sample_tile(p.ctx_s8 + bb * 64 * HWs8, 64, HWs8, offs8, w8x, w8y, bufB, S64, 0);
  sample_tile(p.feat_s8 + bb * 128 * HWs8, 128, HWs8, offs8, w8x, w8y, bufA, S128, 0);
  __syncthreads();

  // h1 = f8 + sig(g1)*(fctx@Wc+bc)   B(72) -> A(136), res A
  mfma_layer<2, 3>(p.ws + OFF_WC, p.bc, bufB, S64, 64, bufA, S128, p.g1, bufA, S128);
  __syncthreads();
  // m1 = gelu(h1@W1+b1)              A(136) -> B(264)
  mfma_layer<4, 1>(p.ws + OFF_W1, p.b1, bufA, S128, 128, bufB, S256, nullptr, nullptr, 0);
  __syncthreads();
  // h2 = m1@W2+b2                    B(264) -> A(136)
  mfma_layer<2, 0>(p.ws + OFF_W2, p.b2, bufB, S256, 256, bufA, S128, nullptr, nullptr, 0);
  __syncthreads();
  // f16 -> B(136)
  sample_tile(p.feat_s16 + bb * 128 * HWs16, 128, HWs16, offs16, w16x, w16y, bufB, S128, 0);
  __syncthreads();
  // h3 = f16 + sig(g2)*(h2@Wp+bp)    A(136) -> B(136), res B
  mfma_layer<2, 3>(p.ws + OFF_WP, p.bp, bufA, S128, 128, bufB, S128, p.g2, bufB, S128);
  __syncthreads();
  // m2 = gelu(h3@W3+b3)              B(136) -> A(264)
  mfma_layer<4, 1>(p.ws + OFF_W3, p.b3, bufB, S128, 128, bufA, S256, nullptr, nullptr, 0);
  __syncthreads();
  // fused = m2@W4+b4 -> B(296) cols 0..127 ; f1_warped -> cols 128..255 ;
  // extras cols 256..259 ; zero-pad 260..287  (disjoint byte regions)
  sample_tile(p.feat1_s8 + bb * 128 * HWs8, 128, HWs8, offsW, wWx, wWy, bufB, S288, 128);
  if (t < MP) {
    unsigned short* rowp = bufB + t * S288;
    rowp[256] = f2bf(gxA[t]);
    rowp[257] = f2bf(gyA[t]);
    rowp[258] = f2bf(caxA[t] * (1.0f / WF));
    rowp[259] = f2bf(cayA[t] * (1.0f / HF));
    for (int j2 = 260; j2 < 288; ++j2) rowp[j2] = 0;
  }
  mfma_layer<2, 0>(p.ws + OFF_W4, p.b4, bufA, S256, 256, bufB, S288, nullptr, nullptr, 0);
  __syncthreads();
  // flow head
  mfma_layer<4, 2>(p.ws + OFF_H0, p.h0b, bufB, S288, 288, bufA, S256, nullptr, nullptr, 0);
  __syncthreads();
  mfma_layer<2, 2>(p.ws + OFF_H1, p.h1b, bufA, S256, 256, bufB, S128, nullptr, nullptr, 0);
  __syncthreads();
  mfma_layer<1, 2>(p.ws + OFF_H2, p.h2b, bufB, S128, 128, bufA, S64, nullptr, nullptr, 0);
  __syncthreads();

  // final 64->2 + output (fp32)
  if (t < 128) {
    int i = t & 63, comp = t >> 6;
    float acc = p.h3b[comp];
    for (int k = 0; k < 64; ++k)
      acc = fmaf(bf2f(bufA[i * S64 + k]), p.h3w[k * 2 + comp], acc);
    float flow = (comp ? cayA[i] : caxA[i]) + acc * (comp ? (float)HF : (float)WF);
    p.out[((bb * 2 + comp) * HF + y) * WF + xb + i] = flow;
  }
}

extern "C" void kernel_launch(void* const* d_in, const int* in_sizes, int n_in,
                              void* d_out, int out_size, void* d_ws, size_t ws_size,
                              hipStream_t stream) {
  PrepParams pp;
  pp.W[0] = (const float*)d_in[6];   // Wc
  pp.W[1] = (const float*)d_in[9];   // W1
  pp.W[2] = (const float*)d_in[11];  // W2
  pp.W[3] = (const float*)d_in[13];  // Wp
  pp.W[4] = (const float*)d_in[16];  // W3
  pp.W[5] = (const float*)d_in[18];  // W4
  pp.W[6] = (const float*)d_in[20];  // hw0
  pp.W[7] = (const float*)d_in[22];  // hw1
  pp.W[8] = (const float*)d_in[24];  // hw2
  pp.ws = (unsigned short*)d_ws;
  hipLaunchKernelGGL(prep_kernel, dim3((SWZ_TOTAL + NTH - 1) / NTH), dim3(NTH), 0, stream, pp);

  Params p;
  p.feat_s8  = (const float*)d_in[1];
  p.feat1_s8 = (const float*)d_in[2];
  p.feat_s16 = (const float*)d_in[3];
  p.ctx_s8   = (const float*)d_in[4];
  p.coarse   = (const float*)d_in[5];
  p.bc  = (const float*)d_in[7];
  p.g1  = (const float*)d_in[8];
  p.b1  = (const float*)d_in[10];
  p.b2  = (const float*)d_in[12];
  p.bp  = (const float*)d_in[14];
  p.g2  = (const float*)d_in[15];
  p.b3  = (const float*)d_in[17];
  p.b4  = (const float*)d_in[19];
  p.h0b = (const float*)d_in[21];
  p.h1b = (const float*)d_in[23];
  p.h2b = (const float*)d_in[25];
  p.h3w = (const float*)d_in[26];
  p.h3b = (const float*)d_in[27];
  p.ws  = (const unsigned short*)d_ws;
  p.out = (float*)d_out;

  hipLaunchKernelGGL(ifd_kernel, dim3(NBLK), dim3(NTH), 0, stream, p);
}

// Round 4
// 627.699 us; speedup vs baseline: 6.3817x; 1.0463x over previous
//
#include <hip/hip_runtime.h>
#include <math.h>

// ---------------------------------------------------------------------------
// ImplicitFlowDecoder — MFMA bf16, R4: patch-staged samplers (uniform-y rows),
// cheap bf16 pack (v_perm), polynomial GELU, float4 bias loads.
// ---------------------------------------------------------------------------

typedef short bf16x8 __attribute__((ext_vector_type(8)));
typedef float f32x4 __attribute__((ext_vector_type(4)));

constexpr int W8 = 64, H8 = 48, W16g = 32, H16g = 24, WF = 512, HF = 384;
constexpr int HWs8 = W8 * H8;      // 3072
constexpr int HWs16 = W16g * H16g; // 768
constexpr int MP = 64;             // points per block (one output row segment)
constexpr int NTH = 256;
constexpr int BPR = WF / MP;                // 8
constexpr int NBLK = 2 * HF * BPR;          // 6144

// LDS row strides (ushort elems)
constexpr int S64 = 72, S128 = 136, S256 = 264, S288 = 296;

// swizzled bf16 weight offsets in d_ws (elems)
constexpr int OFF_WC = 0;
constexpr int OFF_W1 = 8192;
constexpr int OFF_W2 = 40960;
constexpr int OFF_WP = 73728;
constexpr int OFF_W3 = 90112;
constexpr int OFF_W4 = 122880;
constexpr int OFF_H0 = 155648;   // K padded 260->288
constexpr int OFF_H1 = 229376;
constexpr int OFF_H2 = 262144;
constexpr int SWZ_TOTAL = 270336;

__device__ __forceinline__ unsigned short f2bf(float f) {  // RNE (prep only)
  union { float f; unsigned u; } v; v.f = f;
  unsigned r = (v.u + 0x7fffu + ((v.u >> 16) & 1u)) >> 16;
  return (unsigned short)r;
}
__device__ __forceinline__ float bf2f(unsigned short h) {
  union { unsigned u; float f; } v; v.u = ((unsigned)h) << 16;
  return v.f;
}
// pack two floats to bf16x2 (round-half-up): 3 VALU
__device__ __forceinline__ unsigned pack2bf(float a, float b) {
  unsigned ua = __builtin_bit_cast(unsigned, a) + 0x8000u;
  unsigned ub = __builtin_bit_cast(unsigned, b) + 0x8000u;
  return __builtin_amdgcn_perm(ub, ua, 0x07060302u);  // [ua.b2,ua.b3,ub.b2,ub.b3]
}
// gelu via A&S 7.1.26 erf approx (|err| <= 1.5e-7 abs), branch-free ~12 VALU
__device__ __forceinline__ float gelu_fast(float x) {
  float ax = fabsf(x);
  float z = ax * 0.7071067811865475f;
  float t = __builtin_amdgcn_rcpf(fmaf(0.3275911f, z, 1.0f));
  float poly = fmaf(fmaf(fmaf(fmaf(1.061405429f, t, -1.453152027f), t,
                              1.421413741f), t, -0.284496736f), t, 0.254829592f);
  float y = 1.0f - poly * t * __expf(-z * z);   // erf(|x|/sqrt2)
  return 0.5f * (x + ax * y);
}

// ------------------------------- prep kernel -------------------------------
struct PrepParams { const float* W[9]; unsigned short* ws; };

__global__ void prep_kernel(PrepParams pp) {
  const int K_[9]   = {64, 128, 256, 128, 128, 256, 260, 256, 128};
  const int Kp_[9]  = {64, 128, 256, 128, 128, 256, 288, 256, 128};
  const int N_[9]   = {128, 256, 128, 128, 256, 128, 256, 128, 64};
  const int OFF_[9] = {OFF_WC, OFF_W1, OFF_W2, OFF_WP, OFF_W3, OFF_W4, OFF_H0, OFF_H1, OFF_H2};
  for (int e = blockIdx.x * blockDim.x + threadIdx.x; e < SWZ_TOTAL;
       e += gridDim.x * blockDim.x) {
    int L = 0;
#pragma unroll
    for (int i = 1; i < 9; ++i) if (e >= OFF_[i]) L = i;
    int q = e - OFF_[L];
    int j = q & 7;
    int l = (q >> 3) & 63;
    int r = q >> 9;                 // mt * nks + ks
    int nks = Kp_[L] >> 5;
    int ks = r % nks;
    int mt = r / nks;
    int n = mt * 16 + (l & 15);
    int k = ks * 32 + ((l >> 4) << 3) + j;
    float v = (k < K_[L]) ? pp.W[L][k * N_[L] + n] : 0.0f;
    pp.ws[e] = f2bf(v);
  }
}

// ------------------------------ main kernel --------------------------------
struct Params {
  const float* feat_s8; const float* feat1_s8; const float* feat_s16;
  const float* ctx_s8;  const float* coarse;
  const float* bc; const float* g1; const float* b1; const float* b2;
  const float* bp; const float* g2; const float* b3; const float* b4;
  const float* h0b; const float* h1b; const float* h2b;
  const float* h3w; const float* h3b;
  const unsigned short* ws;
  float* out;
};

__device__ __forceinline__ void bilin_setup(float g, int S, int& i0, int& i1, float& w) {
  float s = (g + 1.0f) * (0.5f * S) - 0.5f;
  float f = floorf(s);
  w = s - f;
  int a = (int)f;
  i0 = min(max(a, 0), S - 1);
  i1 = min(max(a + 1, 0), S - 1);
}

// EP: 0=plain, 1=gelu, 2=relu, 3=gated residual
template<int MT_W, int EP>
__device__ __forceinline__ void mfma_layer(
    const unsigned short* __restrict__ Wsw,
    const float* __restrict__ bias,
    const unsigned short* actIn, int sIn, int K,
    unsigned short* actOut, int sOut,
    const float* __restrict__ gate,
    const unsigned short* res, int sRes)
{
  const int t = threadIdx.x;
  const int l = t & 63;
  const int wv = t >> 6;
  const int nks = K >> 5;
  const int mt0 = wv * MT_W;

  f32x4 acc[MT_W][4];
#pragma unroll
  for (int m = 0; m < MT_W; ++m)
#pragma unroll
    for (int p = 0; p < 4; ++p)
#pragma unroll
      for (int r = 0; r < 4; ++r) acc[m][p][r] = 0.0f;

  const unsigned short* bbase = actIn + (l & 15) * sIn + ((l >> 4) << 3);
  const unsigned short* abase = Wsw + ((size_t)mt0 * nks * 512 + l * 8);

  for (int ks = 0; ks < nks; ++ks) {
    bf16x8 B[4];
#pragma unroll
    for (int p = 0; p < 4; ++p)
      B[p] = *(const bf16x8*)(bbase + p * 16 * sIn + ks * 32);
#pragma unroll
    for (int m = 0; m < MT_W; ++m) {
      bf16x8 A = *(const bf16x8*)(abase + (m * nks + ks) * 512);
#pragma unroll
      for (int p = 0; p < 4; ++p)
        acc[m][p] = __builtin_amdgcn_mfma_f32_16x16x32_bf16(A, B[p], acc[m][p], 0, 0, 0);
    }
  }

#pragma unroll
  for (int m = 0; m < MT_W; ++m) {
    const int f0 = (mt0 + m) * 16 + ((l >> 4) << 2);
    const float4 bv = *(const float4*)(bias + f0);
    float4 gv;
    if (EP == 3) {
      float4 g = *(const float4*)(gate + f0);
      gv.x = __builtin_amdgcn_rcpf(1.0f + __expf(-g.x));
      gv.y = __builtin_amdgcn_rcpf(1.0f + __expf(-g.y));
      gv.z = __builtin_amdgcn_rcpf(1.0f + __expf(-g.z));
      gv.w = __builtin_amdgcn_rcpf(1.0f + __expf(-g.w));
    }
#pragma unroll
    for (int p = 0; p < 4; ++p) {
      const int pt = p * 16 + (l & 15);
      float v[4];
      v[0] = acc[m][p][0] + bv.x; v[1] = acc[m][p][1] + bv.y;
      v[2] = acc[m][p][2] + bv.z; v[3] = acc[m][p][3] + bv.w;
      if (EP == 1) {
#pragma unroll
        for (int r = 0; r < 4; ++r) v[r] = gelu_fast(v[r]);
      } else if (EP == 2) {
#pragma unroll
        for (int r = 0; r < 4; ++r) v[r] = fmaxf(v[r], 0.0f);
      } else if (EP == 3) {
        uint2 rv = *(const uint2*)(res + pt * sRes + f0);
        v[0] = fmaf(gv.x, v[0], bf2f((unsigned short)(rv.x & 0xffffu)));
        v[1] = fmaf(gv.y, v[1], bf2f((unsigned short)(rv.x >> 16)));
        v[2] = fmaf(gv.z, v[2], bf2f((unsigned short)(rv.y & 0xffffu)));
        v[3] = fmaf(gv.w, v[3], bf2f((unsigned short)(rv.y >> 16)));
      }
      uint2 pk;
      pk.x = pack2bf(v[0], v[1]);
      pk.y = pack2bf(v[2], v[3]);
      *(uint2*)(actOut + pt * sOut + f0) = pk;
    }
  }
}

// stage a y-lerped patch: NCOL cols x NCH channels of fm at rows y0/y1
template<int NCOL, int NCH>
__device__ void stage_patch(const float* __restrict__ fm, int HW, int Wimg,
                            int base, int y0, int y1, float wy,
                            float* patch, int PS)
{
  const int items = NCOL * NCH;
  for (int e = threadIdx.x; e < items; e += NTH) {
    int ch = e / NCOL, col = e - ch * NCOL;
    int ca = min(base + col, Wimg - 1);
    const float* pp = fm + ch * HW;
    float v0 = pp[y0 * Wimg + ca];
    float v1 = pp[y1 * Wimg + ca];
    patch[col * PS + ch] = fmaf(wy, v1 - v0, v0);
  }
}

// x-lerp from patch into bf16 B-layout buffer; channel-pair fastest mapping
template<int PAIRS>
__device__ void xlerp_tile(const float* __restrict__ patch, int PS,
                           const int* pc, const float* wxA,
                           unsigned short* outBuf, int sOut)
{
  const int items = MP * PAIRS;
  for (int it = threadIdx.x; it < items; it += NTH) {
    int pr = it & (PAIRS - 1);
    int pt = it / PAIRS;          // PAIRS is 32/64 -> shift
    int cc = pc[pt];
    float wx = wxA[pt];
    float2 a = *(const float2*)(patch + (cc & 0xff) * PS + pr * 2);
    float2 b = *(const float2*)(patch + (cc >> 8) * PS + pr * 2);
    float r0 = fmaf(wx, b.x - a.x, a.x);
    float r1 = fmaf(wx, b.y - a.y, a.y);
    *(unsigned*)(outBuf + pt * sOut + pr * 2) = pack2bf(r0, r1);
  }
}

// gather-based bilinear (warped sample only)
__device__ void gather_tile(const float* __restrict__ fm, int C, int HW,
    const short* offs, const float* wxA, const float* wyA,
    unsigned short* outBuf, int sOut, int colOff)
{
  const int items = MP * (C >> 1);
  for (int it = threadIdx.x; it < items; it += NTH) {
    int i = it & (MP - 1);
    int c2 = it >> 6;
    int o00 = offs[0 * MP + i], o01 = offs[1 * MP + i];
    int o10 = offs[2 * MP + i], o11 = offs[3 * MP + i];
    float wx = wxA[i], wy = wyA[i];
    const float* p0 = fm + (c2 * 2) * HW;
    const float* p1 = p0 + HW;
    float a0 = p0[o00], a1 = p0[o01], a2 = p0[o10], a3 = p0[o11];
    float b0 = p1[o00], b1 = p1[o01], b2 = p1[o10], b3 = p1[o11];
    float ax0 = fmaf(wx, a1 - a0, a0), ax1 = fmaf(wx, a3 - a2, a2);
    float bx0 = fmaf(wx, b1 - b0, b0), bx1 = fmaf(wx, b3 - b2, b2);
    float r0 = fmaf(wy, ax1 - ax0, ax0);
    float r1 = fmaf(wy, bx1 - bx0, bx0);
    *(unsigned*)(outBuf + i * sOut + colOff + c2 * 2) = pack2bf(r0, r1);
  }
}

__global__ __launch_bounds__(256, 2)
void ifd_kernel(Params p)
{
  __shared__ __align__(16) unsigned short bufA[MP * S256];  // 33792 B
  __shared__ __align__(16) unsigned short bufB[MP * S288];  // 37888 B
  __shared__ short offsW[4 * MP];
  __shared__ int pc8[MP], pc16[MP];
  __shared__ float w8x[MP], w16x[MP], wWx[MP], wWy[MP];
  __shared__ float caxA[MP], cayA[MP], gxA[MP], gyA[MP];
  __shared__ int uy8_0, uy8_1, uy16_0, uy16_1, ubase8, ubase16;
  __shared__ float uwy8, uwy16;

  // fp32 patch scratch in bufA tail (beyond the S128 region = 17408 B)
  float* patchF8 = (float*)(bufA + 8704);     // 10 x 130 = 1300 floats
  float* patchC  = patchF8 + 1304;            // 10 x 66  =  660 floats

  const int blk = blockIdx.x;
  const int bb = blk / (HF * BPR);
  const int r = blk % (HF * BPR);
  const int y = r >> 3;
  const int xb = (r & (BPR - 1)) * MP;
  const int t = threadIdx.x;

  if (t < MP) {
    const int i = t;
    const int x = xb + i;
    const float lim = 1.0f - 1e-6f;
    float gx = (x + 0.5f) * (2.0f / WF) - 1.0f;
    float gy = (y + 0.5f) * (2.0f / HF) - 1.0f;
    gx = fminf(fmaxf(gx, -lim), lim);
    gy = fminf(fmaxf(gy, -lim), lim);
    gxA[i] = gx; gyA[i] = gy;

    // uniform patch bases from first point of the row segment
    float gx0 = fminf(fmaxf((xb + 0.5f) * (2.0f / WF) - 1.0f, -lim), lim);
    int base8 = min(max((int)floorf((gx0 + 1.0f) * 32.0f - 0.5f), 0), W8 - 1);
    int base16 = min(max((int)floorf((gx0 + 1.0f) * 16.0f - 0.5f), 0), W16g - 1);

    int x0, x1, y0, y1; float wx, wy;
    bilin_setup(gx, W8, x0, x1, wx);
    bilin_setup(gy, H8, y0, y1, wy);
    pc8[i] = (x0 - base8) | ((x1 - base8) << 8);
    w8x[i] = wx;
    int o00 = y0 * W8 + x0, o01 = y0 * W8 + x1;
    int o10 = y1 * W8 + x0, o11 = y1 * W8 + x1;

    int a0, a1, b0i, b1i; float vx, vy;
    bilin_setup(gx, W16g, a0, a1, vx);
    bilin_setup(gy, H16g, b0i, b1i, vy);
    pc16[i] = (a0 - base16) | ((a1 - base16) << 8);
    w16x[i] = vx;

    if (i == 0) {
      uy8_0 = y0; uy8_1 = y1; uwy8 = wy;
      uy16_0 = b0i; uy16_1 = b1i; uwy16 = vy;
      ubase8 = base8; ubase16 = base16;
    }

    // coarse flow (2ch on s8 grid), scale 8
    const float* cf = p.coarse + bb * 2 * HWs8;
    float c00 = cf[o00], c01 = cf[o01], c10 = cf[o10], c11 = cf[o11];
    float cx0 = fmaf(wx, c01 - c00, c00), cx1 = fmaf(wx, c11 - c10, c10);
    float cfx = fmaf(wy, cx1 - cx0, cx0);
    const float* cf2 = cf + HWs8;
    c00 = cf2[o00]; c01 = cf2[o01]; c10 = cf2[o10]; c11 = cf2[o11];
    cx0 = fmaf(wx, c01 - c00, c00); cx1 = fmaf(wx, c11 - c10, c10);
    float cfy = fmaf(wy, cx1 - cx0, cx0);
    float cax = cfx * 8.0f, cay = cfy * 8.0f;
    caxA[i] = cax; cayA[i] = cay;

    float wxn = gx + cax * (2.0f / WF);
    float wyn = gy + cay * (2.0f / HF);
    wxn = fminf(fmaxf(wxn, -lim), lim);
    wyn = fminf(fmaxf(wyn, -lim), lim);
    int u0, u1, v0, v1; float uw, vw;
    bilin_setup(wxn, W8, u0, u1, uw);
    bilin_setup(wyn, H8, v0, v1, vw);
    offsW[0 * MP + i] = (short)(v0 * W8 + u0);
    offsW[1 * MP + i] = (short)(v0 * W8 + u1);
    offsW[2 * MP + i] = (short)(v1 * W8 + u0);
    offsW[3 * MP + i] = (short)(v1 * W8 + u1);
    wWx[i] = uw; wWy[i] = vw;
  }
  __syncthreads();

  // stage f8 + ctx patches (coalesced, y-lerped)
  stage_patch<10, 128>(p.feat_s8 + bb * 128 * HWs8, HWs8, W8,
                       ubase8, uy8_0, uy8_1, uwy8, patchF8, 130);
  stage_patch<10, 64>(p.ctx_s8 + bb * 64 * HWs8, HWs8, W8,
                      ubase8, uy8_0, uy8_1, uwy8, patchC, 66);
  __syncthreads();
  // x-lerp: f8 -> bufA(S128), ctx -> bufB(S64)
  xlerp_tile<64>(patchF8, 130, pc8, w8x, bufA, S128);
  xlerp_tile<32>(patchC, 66, pc8, w8x, bufB, S64);
  __syncthreads();

  // h1 = f8 + sig(g1)*(fctx@Wc+bc)   B(S64) -> A(S128), res A
  mfma_layer<2, 3>(p.ws + OFF_WC, p.bc, bufB, S64, 64, bufA, S128, p.g1, bufA, S128);
  __syncthreads();
  // m1 = gelu(h1@W1+b1)              A(S128) -> B(S256)
  mfma_layer<4, 1>(p.ws + OFF_W1, p.b1, bufA, S128, 128, bufB, S256, nullptr, nullptr, 0);
  __syncthreads();
  // h2 = m1@W2+b2                    B(S256) -> A(S128)
  mfma_layer<2, 0>(p.ws + OFF_W2, p.b2, bufB, S256, 256, bufA, S128, nullptr, nullptr, 0);
  __syncthreads();
  // stage f16 patch into bufA tail (h2 only occupies S128 region)
  stage_patch<6, 128>(p.feat_s16 + bb * 128 * HWs16, HWs16, W16g,
                      ubase16, uy16_0, uy16_1, uwy16, patchF8, 130);
  __syncthreads();
  // x-lerp f16 -> bufB(S128)
  xlerp_tile<64>(patchF8, 130, pc16, w16x, bufB, S128);
  __syncthreads();
  // h3 = f16 + sig(g2)*(h2@Wp+bp)    A(S128) -> B(S128), res B
  mfma_layer<2, 3>(p.ws + OFF_WP, p.bp, bufA, S128, 128, bufB, S128, p.g2, bufB, S128);
  __syncthreads();
  // m2 = gelu(h3@W3+b3)              B(S128) -> A(S256)
  mfma_layer<4, 1>(p.ws + OFF_W3, p.b3, bufB, S128, 128, bufA, S256, nullptr, nullptr, 0);
  __syncthreads();
  // f1_warped (gather) -> bufB cols 128..255 ; extras cols 256..287 ;
  // fused = m2@W4+b4 -> bufB cols 0..127  (disjoint regions, overlap ok)
  gather_tile(p.feat1_s8 + bb * 128 * HWs8, 128, HWs8, offsW, wWx, wWy, bufB, S288, 128);
  for (int idx = t; idx < MP * 16; idx += NTH) {
    int row = idx >> 4, c = idx & 15;
    unsigned val = 0;
    if (c == 0) val = pack2bf(gxA[row], gyA[row]);
    else if (c == 1) val = pack2bf(caxA[row] * (1.0f / WF), cayA[row] * (1.0f / HF));
    *(unsigned*)(bufB + row * S288 + 256 + c * 2) = val;
  }
  mfma_layer<2, 0>(p.ws + OFF_W4, p.b4, bufA, S256, 256, bufB, S288, nullptr, nullptr, 0);
  __syncthreads();
  // flow head
  mfma_layer<4, 2>(p.ws + OFF_H0, p.h0b, bufB, S288, 288, bufA, S256, nullptr, nullptr, 0);
  __syncthreads();
  mfma_layer<2, 2>(p.ws + OFF_H1, p.h1b, bufA, S256, 256, bufB, S128, nullptr, nullptr, 0);
  __syncthreads();
  mfma_layer<1, 2>(p.ws + OFF_H2, p.h2b, bufB, S128, 128, bufA, S64, nullptr, nullptr, 0);
  __syncthreads();

  // final 64->2 + output (fp32)
  if (t < 128) {
    int i = t & 63, comp = t >> 6;
    float acc = p.h3b[comp];
    for (int k = 0; k < 64; ++k)
      acc = fmaf(bf2f(bufA[i * S64 + k]), p.h3w[k * 2 + comp], acc);
    float flow = (comp ? cayA[i] : caxA[i]) + acc * (comp ? (float)HF : (float)WF);
    p.out[((bb * 2 + comp) * HF + y) * WF + xb + i] = flow;
  }
}

extern "C" void kernel_launch(void* const* d_in, const int* in_sizes, int n_in,
                              void* d_out, int out_size, void* d_ws, size_t ws_size,
                              hipStream_t stream) {
  PrepParams pp;
  pp.W[0] = (const float*)d_in[6];   // Wc
  pp.W[1] = (const float*)d_in[9];   // W1
  pp.W[2] = (const float*)d_in[11];  // W2
  pp.W[3] = (const float*)d_in[13];  // Wp
  pp.W[4] = (const float*)d_in[16];  // W3
  pp.W[5] = (const float*)d_in[18];  // W4
  pp.W[6] = (const float*)d_in[20];  // hw0
  pp.W[7] = (const float*)d_in[22];  // hw1
  pp.W[8] = (const float*)d_in[24];  // hw2
  pp.ws = (unsigned short*)d_ws;
  hipLaunchKernelGGL(prep_kernel, dim3((SWZ_TOTAL + NTH - 1) / NTH), dim3(NTH), 0, stream, pp);

  Params p;
  p.feat_s8  = (const float*)d_in[1];
  p.feat1_s8 = (const float*)d_in[2];
  p.feat_s16 = (const float*)d_in[3];
  p.ctx_s8   = (const float*)d_in[4];
  p.coarse   = (const float*)d_in[5];
  p.bc  = (const float*)d_in[7];
  p.g1  = (const float*)d_in[8];
  p.b1  = (const float*)d_in[10];
  p.b2  = (const float*)d_in[12];
  p.bp  = (const float*)d_in[14];
  p.g2  = (const float*)d_in[15];
  p.b3  = (const float*)d_in[17];
  p.b4  = (const float*)d_in[19];
  p.h0b = (const float*)d_in[21];
  p.h1b = (const float*)d_in[23];
  p.h2b = (const float*)d_in[25];
  p.h3w = (const float*)d_in[26];
  p.h3b = (const float*)d_in[27];
  p.ws  = (const unsigned short*)d_ws;
  p.out = (float*)d_out;

  hipLaunchKernelGGL(ifd_kernel, dim3(NBLK), dim3(NTH), 0, stream, p);
}

// Round 5
// 524.564 us; speedup vs baseline: 7.6365x; 1.1966x over previous
//
#include <hip/hip_runtime.h>
#include <math.h>

// ---------------------------------------------------------------------------
// ImplicitFlowDecoder — MFMA bf16, R5: single in-place LDS activation buffer
// (50 KB -> 3 blocks/CU), f16 staging overlapped with Wc, vectorized tail.
// ---------------------------------------------------------------------------

typedef short bf16x8 __attribute__((ext_vector_type(8)));
typedef float f32x4 __attribute__((ext_vector_type(4)));

constexpr int W8 = 64, H8 = 48, W16g = 32, H16g = 24, WF = 512, HF = 384;
constexpr int HWs8 = W8 * H8;      // 3072
constexpr int HWs16 = W16g * H16g; // 768
constexpr int MP = 64;             // points per block (one output row segment)
constexpr int NTH = 256;
constexpr int BPR = WF / MP;                // 8
constexpr int NBLK = 2 * HF * BPR;          // 6144

constexpr int S = 296;  // single-buffer row stride (ushorts); 2-way banks on b128

// swizzled bf16 weight offsets in d_ws (elems)
constexpr int OFF_WC = 0;
constexpr int OFF_W1 = 8192;
constexpr int OFF_W2 = 40960;
constexpr int OFF_WP = 73728;
constexpr int OFF_W3 = 90112;
constexpr int OFF_W4 = 122880;
constexpr int OFF_H0 = 155648;   // K padded 260->288
constexpr int OFF_H1 = 229376;
constexpr int OFF_H2 = 262144;
constexpr int SWZ_TOTAL = 270336;

__device__ __forceinline__ unsigned short f2bf(float f) {  // RNE (prep only)
  union { float f; unsigned u; } v; v.f = f;
  unsigned r = (v.u + 0x7fffu + ((v.u >> 16) & 1u)) >> 16;
  return (unsigned short)r;
}
__device__ __forceinline__ float bf2f(unsigned short h) {
  union { unsigned u; float f; } v; v.u = ((unsigned)h) << 16;
  return v.f;
}
// pack two floats to bf16x2 (round-half-up): 3 VALU
__device__ __forceinline__ unsigned pack2bf(float a, float b) {
  unsigned ua = __builtin_bit_cast(unsigned, a) + 0x8000u;
  unsigned ub = __builtin_bit_cast(unsigned, b) + 0x8000u;
  return __builtin_amdgcn_perm(ub, ua, 0x07060302u);
}
// gelu via A&S 7.1.26 erf approx (|err| <= 1.5e-7 abs)
__device__ __forceinline__ float gelu_fast(float x) {
  float ax = fabsf(x);
  float z = ax * 0.7071067811865475f;
  float t = __builtin_amdgcn_rcpf(fmaf(0.3275911f, z, 1.0f));
  float poly = fmaf(fmaf(fmaf(fmaf(1.061405429f, t, -1.453152027f), t,
                              1.421413741f), t, -0.284496736f), t, 0.254829592f);
  float y = 1.0f - poly * t * __expf(-z * z);   // erf(|x|/sqrt2)
  return 0.5f * (x + ax * y);
}

// ------------------------------- prep kernel -------------------------------
struct PrepParams { const float* W[9]; unsigned short* ws; };

__global__ void prep_kernel(PrepParams pp) {
  const int K_[9]   = {64, 128, 256, 128, 128, 256, 260, 256, 128};
  const int Kp_[9]  = {64, 128, 256, 128, 128, 256, 288, 256, 128};
  const int N_[9]   = {128, 256, 128, 128, 256, 128, 256, 128, 64};
  const int OFF_[9] = {OFF_WC, OFF_W1, OFF_W2, OFF_WP, OFF_W3, OFF_W4, OFF_H0, OFF_H1, OFF_H2};
  for (int e = blockIdx.x * blockDim.x + threadIdx.x; e < SWZ_TOTAL;
       e += gridDim.x * blockDim.x) {
    int L = 0;
#pragma unroll
    for (int i = 1; i < 9; ++i) if (e >= OFF_[i]) L = i;
    int q = e - OFF_[L];
    int j = q & 7;
    int l = (q >> 3) & 63;
    int r = q >> 9;                 // mt * nks + ks
    int nks = Kp_[L] >> 5;
    int ks = r % nks;
    int mt = r / nks;
    int n = mt * 16 + (l & 15);
    int k = ks * 32 + ((l >> 4) << 3) + j;
    float v = (k < K_[L]) ? pp.W[L][k * N_[L] + n] : 0.0f;
    pp.ws[e] = f2bf(v);
  }
}

// ------------------------------ main kernel --------------------------------
struct Params {
  const float* feat_s8; const float* feat1_s8; const float* feat_s16;
  const float* ctx_s8;  const float* coarse;
  const float* bc; const float* g1; const float* b1; const float* b2;
  const float* bp; const float* g2; const float* b3; const float* b4;
  const float* h0b; const float* h1b; const float* h2b;
  const float* h3w; const float* h3b;
  const unsigned short* ws;
  float* out;
};

__device__ __forceinline__ void bilin_setup(float g, int Sg, int& i0, int& i1, float& w) {
  float s = (g + 1.0f) * (0.5f * Sg) - 0.5f;
  float f = floorf(s);
  w = s - f;
  int a = (int)f;
  i0 = min(max(a, 0), Sg - 1);
  i1 = min(max(a + 1, 0), Sg - 1);
}

// EP: 0=plain, 1=gelu, 2=relu, 3=gated residual.
// SYNC: barrier between all B-reads and epilogue stores (in-place safety).
template<int MT_W, int EP, bool SYNC>
__device__ __forceinline__ void mfma_layer(
    const unsigned short* __restrict__ Wsw,
    const float* __restrict__ bias,
    const unsigned short* actIn, int K,
    unsigned short* actOut,
    const float* __restrict__ gate,
    const unsigned short* res)
{
  const int t = threadIdx.x;
  const int l = t & 63;
  const int wv = t >> 6;
  const int nks = K >> 5;
  const int mt0 = wv * MT_W;

  f32x4 acc[MT_W][4];
#pragma unroll
  for (int m = 0; m < MT_W; ++m)
#pragma unroll
    for (int p = 0; p < 4; ++p)
#pragma unroll
      for (int r = 0; r < 4; ++r) acc[m][p][r] = 0.0f;

  const unsigned short* bbase = actIn + (l & 15) * S + ((l >> 4) << 3);
  const unsigned short* abase = Wsw + ((size_t)mt0 * nks * 512 + l * 8);

  for (int ks = 0; ks < nks; ++ks) {
    bf16x8 B[4];
#pragma unroll
    for (int p = 0; p < 4; ++p)
      B[p] = *(const bf16x8*)(bbase + p * 16 * S + ks * 32);
#pragma unroll
    for (int m = 0; m < MT_W; ++m) {
      bf16x8 A = *(const bf16x8*)(abase + (m * nks + ks) * 512);
#pragma unroll
      for (int p = 0; p < 4; ++p)
        acc[m][p] = __builtin_amdgcn_mfma_f32_16x16x32_bf16(A, B[p], acc[m][p], 0, 0, 0);
    }
  }

  if (SYNC) __syncthreads();   // all B-reads done before any in-place store

#pragma unroll
  for (int m = 0; m < MT_W; ++m) {
    const int f0 = (mt0 + m) * 16 + ((l >> 4) << 2);
    const float4 bv = *(const float4*)(bias + f0);
    float4 gv;
    if (EP == 3) {
      float4 g = *(const float4*)(gate + f0);
      gv.x = __builtin_amdgcn_rcpf(1.0f + __expf(-g.x));
      gv.y = __builtin_amdgcn_rcpf(1.0f + __expf(-g.y));
      gv.z = __builtin_amdgcn_rcpf(1.0f + __expf(-g.z));
      gv.w = __builtin_amdgcn_rcpf(1.0f + __expf(-g.w));
    }
#pragma unroll
    for (int p = 0; p < 4; ++p) {
      const int pt = p * 16 + (l & 15);
      float v[4];
      v[0] = acc[m][p][0] + bv.x; v[1] = acc[m][p][1] + bv.y;
      v[2] = acc[m][p][2] + bv.z; v[3] = acc[m][p][3] + bv.w;
      if (EP == 1) {
#pragma unroll
        for (int r = 0; r < 4; ++r) v[r] = gelu_fast(v[r]);
      } else if (EP == 2) {
#pragma unroll
        for (int r = 0; r < 4; ++r) v[r] = fmaxf(v[r], 0.0f);
      } else if (EP == 3) {
        uint2 rv = *(const uint2*)(res + pt * S + f0);
        v[0] = fmaf(gv.x, v[0], bf2f((unsigned short)(rv.x & 0xffffu)));
        v[1] = fmaf(gv.y, v[1], bf2f((unsigned short)(rv.x >> 16)));
        v[2] = fmaf(gv.z, v[2], bf2f((unsigned short)(rv.y & 0xffffu)));
        v[3] = fmaf(gv.w, v[3], bf2f((unsigned short)(rv.y >> 16)));
      }
      uint2 pk;
      pk.x = pack2bf(v[0], v[1]);
      pk.y = pack2bf(v[2], v[3]);
      *(uint2*)(actOut + pt * S + f0) = pk;
    }
  }
}

// stage a y-lerped patch: NCOL cols x NCH channels of fm at rows y0/y1
template<int NCOL, int NCH>
__device__ void stage_patch(const float* __restrict__ fm, int HW, int Wimg,
                            int base, int y0, int y1, float wy,
                            float* patch, int PS)
{
  const int items = NCOL * NCH;
  for (int e = threadIdx.x; e < items; e += NTH) {
    int ch = e / NCOL, col = e - ch * NCOL;
    int ca = min(base + col, Wimg - 1);
    const float* pp = fm + ch * HW;
    float v0 = pp[y0 * Wimg + ca];
    float v1 = pp[y1 * Wimg + ca];
    patch[col * PS + ch] = fmaf(wy, v1 - v0, v0);
  }
}

// x-lerp from patch into bf16 B-layout buffer
template<int PAIRS>
__device__ void xlerp_tile(const float* __restrict__ patch, int PS,
                           const int* pc, const float* wxA,
                           unsigned short* outBuf, int colOff)
{
  const int items = MP * PAIRS;
  for (int it = threadIdx.x; it < items; it += NTH) {
    int pr = it & (PAIRS - 1);
    int pt = it / PAIRS;
    int cc = pc[pt];
    float wx = wxA[pt];
    float2 a = *(const float2*)(patch + (cc & 0xff) * PS + pr * 2);
    float2 b = *(const float2*)(patch + (cc >> 8) * PS + pr * 2);
    float r0 = fmaf(wx, b.x - a.x, a.x);
    float r1 = fmaf(wx, b.y - a.y, a.y);
    *(unsigned*)(outBuf + pt * S + colOff + pr * 2) = pack2bf(r0, r1);
  }
}

// gather-based bilinear (warped sample only)
__device__ void gather_tile(const float* __restrict__ fm, int C, int HW,
    const short* offs, const float* wxA, const float* wyA,
    unsigned short* outBuf, int colOff)
{
  const int items = MP * (C >> 1);
  for (int it = threadIdx.x; it < items; it += NTH) {
    int i = it & (MP - 1);
    int c2 = it >> 6;
    int o00 = offs[0 * MP + i], o01 = offs[1 * MP + i];
    int o10 = offs[2 * MP + i], o11 = offs[3 * MP + i];
    float wx = wxA[i], wy = wyA[i];
    const float* p0 = fm + (c2 * 2) * HW;
    const float* p1 = p0 + HW;
    float a0 = p0[o00], a1 = p0[o01], a2 = p0[o10], a3 = p0[o11];
    float b0 = p1[o00], b1 = p1[o01], b2 = p1[o10], b3 = p1[o11];
    float ax0 = fmaf(wx, a1 - a0, a0), ax1 = fmaf(wx, a3 - a2, a2);
    float bx0 = fmaf(wx, b1 - b0, b0), bx1 = fmaf(wx, b3 - b2, b2);
    float r0 = fmaf(wy, ax1 - ax0, ax0);
    float r1 = fmaf(wy, bx1 - bx0, bx0);
    *(unsigned*)(outBuf + i * S + colOff + c2 * 2) = pack2bf(r0, r1);
  }
}

__global__ __launch_bounds__(256, 3)
void ifd_kernel(Params p)
{
  __shared__ __align__(16) unsigned short buf[MP * S];   // 37888 B
  __shared__ __align__(16) float patchA[10 * 130];        // 5200 B (f8, then f16)
  __shared__ __align__(16) float patchC[10 * 66];         // 2640 B
  __shared__ float wH3[128];
  __shared__ short offsW[4 * MP];
  __shared__ int pc8[MP], pc16[MP];
  __shared__ float w8x[MP], w16x[MP], wWx[MP], wWy[MP];
  __shared__ float caxA[MP], cayA[MP], gxA[MP], gyA[MP];
  __shared__ int uy8_0, uy8_1, uy16_0, uy16_1, ubase8, ubase16;
  __shared__ float uwy8, uwy16;

  const int blk = blockIdx.x;
  const int bb = blk / (HF * BPR);
  const int r = blk % (HF * BPR);
  const int y = r >> 3;
  const int xb = (r & (BPR - 1)) * MP;
  const int t = threadIdx.x;

  if (t >= 128 && t < 256) wH3[t - 128] = p.h3w[t - 128];
  if (t < MP) {
    const int i = t;
    const int x = xb + i;
    const float lim = 1.0f - 1e-6f;
    float gx = (x + 0.5f) * (2.0f / WF) - 1.0f;
    float gy = (y + 0.5f) * (2.0f / HF) - 1.0f;
    gx = fminf(fmaxf(gx, -lim), lim);
    gy = fminf(fmaxf(gy, -lim), lim);
    gxA[i] = gx; gyA[i] = gy;

    float gx0 = fminf(fmaxf((xb + 0.5f) * (2.0f / WF) - 1.0f, -lim), lim);
    int base8 = min(max((int)floorf((gx0 + 1.0f) * 32.0f - 0.5f), 0), W8 - 1);
    int base16 = min(max((int)floorf((gx0 + 1.0f) * 16.0f - 0.5f), 0), W16g - 1);

    int x0, x1, y0, y1; float wx, wy;
    bilin_setup(gx, W8, x0, x1, wx);
    bilin_setup(gy, H8, y0, y1, wy);
    pc8[i] = (x0 - base8) | ((x1 - base8) << 8);
    w8x[i] = wx;
    int o00 = y0 * W8 + x0, o01 = y0 * W8 + x1;
    int o10 = y1 * W8 + x0, o11 = y1 * W8 + x1;

    int a0, a1, b0i, b1i; float vx, vy;
    bilin_setup(gx, W16g, a0, a1, vx);
    bilin_setup(gy, H16g, b0i, b1i, vy);
    pc16[i] = (a0 - base16) | ((a1 - base16) << 8);
    w16x[i] = vx;

    if (i == 0) {
      uy8_0 = y0; uy8_1 = y1; uwy8 = wy;
      uy16_0 = b0i; uy16_1 = b1i; uwy16 = vy;
      ubase8 = base8; ubase16 = base16;
    }

    const float* cf = p.coarse + bb * 2 * HWs8;
    float c00 = cf[o00], c01 = cf[o01], c10 = cf[o10], c11 = cf[o11];
    float cx0 = fmaf(wx, c01 - c00, c00), cx1 = fmaf(wx, c11 - c10, c10);
    float cfx = fmaf(wy, cx1 - cx0, cx0);
    const float* cf2 = cf + HWs8;
    c00 = cf2[o00]; c01 = cf2[o01]; c10 = cf2[o10]; c11 = cf2[o11];
    cx0 = fmaf(wx, c01 - c00, c00); cx1 = fmaf(wx, c11 - c10, c10);
    float cfy = fmaf(wy, cx1 - cx0, cx0);
    float cax = cfx * 8.0f, cay = cfy * 8.0f;
    caxA[i] = cax; cayA[i] = cay;

    float wxn = gx + cax * (2.0f / WF);
    float wyn = gy + cay * (2.0f / HF);
    wxn = fminf(fmaxf(wxn, -lim), lim);
    wyn = fminf(fmaxf(wyn, -lim), lim);
    int u0, u1, v0, v1; float uw, vw;
    bilin_setup(wxn, W8, u0, u1, uw);
    bilin_setup(wyn, H8, v0, v1, vw);
    offsW[0 * MP + i] = (short)(v0 * W8 + u0);
    offsW[1 * MP + i] = (short)(v0 * W8 + u1);
    offsW[2 * MP + i] = (short)(v1 * W8 + u0);
    offsW[3 * MP + i] = (short)(v1 * W8 + u1);
    wWx[i] = uw; wWy[i] = vw;
  }
  __syncthreads();

  // stage f8 + ctx patches (coalesced, y-lerped)
  stage_patch<10, 128>(p.feat_s8 + bb * 128 * HWs8, HWs8, W8,
                       ubase8, uy8_0, uy8_1, uwy8, patchA, 130);
  stage_patch<10, 64>(p.ctx_s8 + bb * 64 * HWs8, HWs8, W8,
                      ubase8, uy8_0, uy8_1, uwy8, patchC, 66);
  __syncthreads();
  xlerp_tile<64>(patchA, 130, pc8, w8x, buf, 128);   // f8  -> cols [128:256)
  xlerp_tile<32>(patchC, 66, pc8, w8x, buf, 0);      // ctx -> cols [0:64)
  __syncthreads();

  // Wc: in [0:64) K=64 -> out [128:256), residual same cols (per-thread RAW ok)
  mfma_layer<2, 3, false>(p.ws + OFF_WC, p.bc, buf, 64, buf + 128, p.g1, buf + 128);
  // overlap: stage f16 patch (patchA dead; its readers finished pre-barrier)
  stage_patch<6, 128>(p.feat_s16 + bb * 128 * HWs16, HWs16, W16g,
                      ubase16, uy16_0, uy16_1, uwy16, patchA, 130);
  __syncthreads();
  // W1: in [128:256) K=128 -> out [0:256)   (overlaps input -> SYNC)
  mfma_layer<4, 1, true>(p.ws + OFF_W1, p.b1, buf + 128, 128, buf, nullptr, nullptr);
  __syncthreads();
  // W2: in [0:256) K=256 -> out [0:128)     (SYNC)
  mfma_layer<2, 0, true>(p.ws + OFF_W2, p.b2, buf, 256, buf, nullptr, nullptr);
  // f16 x-lerp -> cols [128:256)  (past W2's internal barrier: all reads done)
  xlerp_tile<64>(patchA, 130, pc16, w16x, buf, 128);
  __syncthreads();
  // Wp: in [0:128) -> out [128:256), residual same cols
  mfma_layer<2, 3, false>(p.ws + OFF_WP, p.bp, buf, 128, buf + 128, p.g2, buf + 128);
  __syncthreads();
  // W3: in [128:256) K=128 -> out [0:256)   (SYNC)
  mfma_layer<4, 1, true>(p.ws + OFF_W3, p.b3, buf + 128, 128, buf, nullptr, nullptr);
  __syncthreads();
  // W4: in [0:256) K=256 -> out [0:128)     (SYNC); then f1_warped -> [128:256),
  // extras -> [256:288)  (past W4's internal barrier)
  mfma_layer<2, 0, true>(p.ws + OFF_W4, p.b4, buf, 256, buf, nullptr, nullptr);
  gather_tile(p.feat1_s8 + bb * 128 * HWs8, 128, HWs8, offsW, wWx, wWy, buf, 128);
  for (int idx = t; idx < MP * 16; idx += NTH) {
    int row = idx >> 4, c = idx & 15;
    unsigned val = 0;
    if (c == 0) val = pack2bf(gxA[row], gyA[row]);
    else if (c == 1) val = pack2bf(caxA[row] * (1.0f / WF), cayA[row] * (1.0f / HF));
    *(unsigned*)(buf + row * S + 256 + c * 2) = val;
  }
  __syncthreads();
  // flow head, all in-place
  mfma_layer<4, 2, true>(p.ws + OFF_H0, p.h0b, buf, 288, buf, nullptr, nullptr);
  __syncthreads();
  mfma_layer<2, 2, true>(p.ws + OFF_H1, p.h1b, buf, 256, buf, nullptr, nullptr);
  __syncthreads();
  mfma_layer<1, 2, true>(p.ws + OFF_H2, p.h2b, buf, 128, buf, nullptr, nullptr);
  __syncthreads();

  // final 64->2 + output (fp32), vectorized LDS reads + LDS weights
  if (t < 128) {
    int i = t & 63, comp = t >> 6;
    float acc = p.h3b[comp];
    const unsigned short* rowp = buf + i * S;
#pragma unroll
    for (int k8 = 0; k8 < 8; ++k8) {
      uint4 av = *(const uint4*)(rowp + k8 * 8);
      const float* wp = wH3 + k8 * 16 + comp;
      unsigned u0 = av.x, u1 = av.y, u2 = av.z, u3 = av.w;
      acc = fmaf(__builtin_bit_cast(float, u0 << 16),          wp[0], acc);
      acc = fmaf(__builtin_bit_cast(float, u0 & 0xffff0000u),  wp[2], acc);
      acc = fmaf(__builtin_bit_cast(float, u1 << 16),          wp[4], acc);
      acc = fmaf(__builtin_bit_cast(float, u1 & 0xffff0000u),  wp[6], acc);
      acc = fmaf(__builtin_bit_cast(float, u2 << 16),          wp[8], acc);
      acc = fmaf(__builtin_bit_cast(float, u2 & 0xffff0000u),  wp[10], acc);
      acc = fmaf(__builtin_bit_cast(float, u3 << 16),          wp[12], acc);
      acc = fmaf(__builtin_bit_cast(float, u3 & 0xffff0000u),  wp[14], acc);
    }
    float flow = (comp ? cayA[i] : caxA[i]) + acc * (comp ? (float)HF : (float)WF);
    p.out[((bb * 2 + comp) * HF + y) * WF + xb + i] = flow;
  }
}

extern "C" void kernel_launch(void* const* d_in, const int* in_sizes, int n_in,
                              void* d_out, int out_size, void* d_ws, size_t ws_size,
                              hipStream_t stream) {
  PrepParams pp;
  pp.W[0] = (const float*)d_in[6];   // Wc
  pp.W[1] = (const float*)d_in[9];   // W1
  pp.W[2] = (const float*)d_in[11];  // W2
  pp.W[3] = (const float*)d_in[13];  // Wp
  pp.W[4] = (const float*)d_in[16];  // W3
  pp.W[5] = (const float*)d_in[18];  // W4
  pp.W[6] = (const float*)d_in[20];  // hw0
  pp.W[7] = (const float*)d_in[22];  // hw1
  pp.W[8] = (const float*)d_in[24];  // hw2
  pp.ws = (unsigned short*)d_ws;
  hipLaunchKernelGGL(prep_kernel, dim3((SWZ_TOTAL + NTH - 1) / NTH), dim3(NTH), 0, stream, pp);

  Params p;
  p.feat_s8  = (const float*)d_in[1];
  p.feat1_s8 = (const float*)d_in[2];
  p.feat_s16 = (const float*)d_in[3];
  p.ctx_s8   = (const float*)d_in[4];
  p.coarse   = (const float*)d_in[5];
  p.bc  = (const float*)d_in[7];
  p.g1  = (const float*)d_in[8];
  p.b1  = (const float*)d_in[10];
  p.b2  = (const float*)d_in[12];
  p.bp  = (const float*)d_in[14];
  p.g2  = (const float*)d_in[15];
  p.b3  = (const float*)d_in[17];
  p.b4  = (const float*)d_in[19];
  p.h0b = (const float*)d_in[21];
  p.h1b = (const float*)d_in[23];
  p.h2b = (const float*)d_in[25];
  p.h3w = (const float*)d_in[26];
  p.h3b = (const float*)d_in[27];
  p.ws  = (const unsigned short*)d_ws;
  p.out = (float*)d_out;

  hipLaunchKernelGGL(ifd_kernel, dim3(NBLK), dim3(NTH), 0, stream, p);
}

// Round 6
// 503.491 us; speedup vs baseline: 7.9561x; 1.0419x over previous
//
#include <hip/hip_runtime.h>
#include <math.h>

// ---------------------------------------------------------------------------
// ImplicitFlowDecoder — R6: 32x32x16 MFMA (half the MFMA instrs, faster pipe),
// bias preloaded into accumulator, v_cvt_pk_bf16_f32 pack when available.
// Single in-place LDS activation buffer, 3 blocks/CU.
// ---------------------------------------------------------------------------

typedef short bf16x8 __attribute__((ext_vector_type(8)));
typedef float f32x16 __attribute__((ext_vector_type(16)));

constexpr int W8 = 64, H8 = 48, W16g = 32, H16g = 24, WF = 512, HF = 384;
constexpr int HWs8 = W8 * H8;      // 3072
constexpr int HWs16 = W16g * H16g; // 768
constexpr int MP = 64;             // points per block (one output row segment)
constexpr int NTH = 256;
constexpr int BPR = WF / MP;                // 8
constexpr int NBLK = 2 * HF * BPR;          // 6144

constexpr int S = 296;  // row stride (ushorts)

// swizzled bf16 weight offsets in d_ws (elems) — totals unchanged from R5
constexpr int OFF_WC = 0;
constexpr int OFF_W1 = 8192;
constexpr int OFF_W2 = 40960;
constexpr int OFF_WP = 73728;
constexpr int OFF_W3 = 90112;
constexpr int OFF_W4 = 122880;
constexpr int OFF_H0 = 155648;   // K padded 260->288
constexpr int OFF_H1 = 229376;
constexpr int OFF_H2 = 262144;
constexpr int SWZ_TOTAL = 270336;

__device__ __forceinline__ unsigned short f2bf(float f) {  // RNE (prep only)
  union { float f; unsigned u; } v; v.f = f;
  unsigned r = (v.u + 0x7fffu + ((v.u >> 16) & 1u)) >> 16;
  return (unsigned short)r;
}
__device__ __forceinline__ float bf2f(unsigned short h) {
  union { unsigned u; float f; } v; v.u = ((unsigned)h) << 16;
  return v.f;
}
// pack two floats to bf16x2: packed-cvt instr if available, else 3-op round-up
#if defined(__has_builtin)
#if __has_builtin(__builtin_amdgcn_cvt_pk_bf16_f32)
#define HAS_PK_BF16 1
#endif
#endif
__device__ __forceinline__ unsigned pack2bf(float a, float b) {
#ifdef HAS_PK_BF16
  typedef __bf16 bf2_t __attribute__((ext_vector_type(2)));
  bf2_t r = __builtin_amdgcn_cvt_pk_bf16_f32(a, b);
  return __builtin_bit_cast(unsigned, r);
#else
  unsigned ua = __builtin_bit_cast(unsigned, a) + 0x8000u;
  unsigned ub = __builtin_bit_cast(unsigned, b) + 0x8000u;
  return __builtin_amdgcn_perm(ub, ua, 0x07060302u);
#endif
}
// gelu via A&S 7.1.26 erf approx (|err| <= 1.5e-7 abs)
__device__ __forceinline__ float gelu_fast(float x) {
  float ax = fabsf(x);
  float z = ax * 0.7071067811865475f;
  float t = __builtin_amdgcn_rcpf(fmaf(0.3275911f, z, 1.0f));
  float poly = fmaf(fmaf(fmaf(fmaf(1.061405429f, t, -1.453152027f), t,
                              1.421413741f), t, -0.284496736f), t, 0.254829592f);
  float y = 1.0f - poly * t * __expf(-z * z);   // erf(|x|/sqrt2)
  return 0.5f * (x + ax * y);
}

// ------------------------------- prep kernel -------------------------------
// A-operand swizzle for 32x32x16: fragment (mt, ks) at (mt*nks+ks)*512;
// lane l elem j = W[k = ks*16 + (l>>5)*8 + j][n = mt*32 + (l&31)]
struct PrepParams { const float* W[9]; unsigned short* ws; };

__global__ void prep_kernel(PrepParams pp) {
  const int K_[9]   = {64, 128, 256, 128, 128, 256, 260, 256, 128};
  const int Kp_[9]  = {64, 128, 256, 128, 128, 256, 288, 256, 128};
  const int N_[9]   = {128, 256, 128, 128, 256, 128, 256, 128, 64};
  const int OFF_[9] = {OFF_WC, OFF_W1, OFF_W2, OFF_WP, OFF_W3, OFF_W4, OFF_H0, OFF_H1, OFF_H2};
  for (int e = blockIdx.x * blockDim.x + threadIdx.x; e < SWZ_TOTAL;
       e += gridDim.x * blockDim.x) {
    int L = 0;
#pragma unroll
    for (int i = 1; i < 9; ++i) if (e >= OFF_[i]) L = i;
    int q = e - OFF_[L];
    int j = q & 7;
    int l = (q >> 3) & 63;
    int r = q >> 9;                 // mt * nks + ks
    int nks = Kp_[L] >> 4;
    int ks = r % nks;
    int mt = r / nks;
    int n = mt * 32 + (l & 31);
    int k = ks * 16 + ((l >> 5) << 3) + j;
    float v = (k < K_[L]) ? pp.W[L][k * N_[L] + n] : 0.0f;
    pp.ws[e] = f2bf(v);
  }
}

// ------------------------------ main kernel --------------------------------
struct Params {
  const float* feat_s8; const float* feat1_s8; const float* feat_s16;
  const float* ctx_s8;  const float* coarse;
  const float* bc; const float* g1; const float* b1; const float* b2;
  const float* bp; const float* g2; const float* b3; const float* b4;
  const float* h0b; const float* h1b; const float* h2b;
  const float* h3w; const float* h3b;
  const unsigned short* ws;
  float* out;
};

__device__ __forceinline__ void bilin_setup(float g, int Sg, int& i0, int& i1, float& w) {
  float s = (g + 1.0f) * (0.5f * Sg) - 0.5f;
  float f = floorf(s);
  w = s - f;
  int a = (int)f;
  i0 = min(max(a, 0), Sg - 1);
  i1 = min(max(a + 1, 0), Sg - 1);
}

// 32x32x16 MFMA layer. MT = m-tiles(32) per wave; NT = n-tiles per wave
// (NT=2: wave covers both 32-point halves; NT=1: wave wv -> nt = wv&1).
// EP: 0=plain, 1=gelu, 2=relu, 3=gated residual.
// SYNC: barrier between all B-reads and epilogue stores (in-place safety).
template<int MT, int NT, int EP, bool SYNC>
__device__ __forceinline__ void mfma_layer(
    const unsigned short* __restrict__ Wsw,
    const float* __restrict__ bias,
    const unsigned short* actIn, int K,
    unsigned short* actOut,
    const float* __restrict__ gate,
    const unsigned short* res)
{
  const int t = threadIdx.x;
  const int l = t & 63;
  const int wv = t >> 6;
  const int nks = K >> 4;
  const int mt0 = (NT == 2) ? wv * MT : (wv >> 1);
  const int ntb = (NT == 2) ? 0 : (wv & 1);
  const int lh = l >> 5;          // 0/1
  const int ll = l & 31;

  // bias preloaded into accumulator: C/D row = (reg&3) + 8*(reg>>2) + 4*lh
  f32x16 acc[MT][NT];
#pragma unroll
  for (int m = 0; m < MT; ++m) {
#pragma unroll
    for (int g = 0; g < 4; ++g) {
      const int f0 = (mt0 + m) * 32 + g * 8 + (lh << 2);
      const float4 bv = *(const float4*)(bias + f0);
#pragma unroll
      for (int nt = 0; nt < NT; ++nt) {
        acc[m][nt][g * 4 + 0] = bv.x; acc[m][nt][g * 4 + 1] = bv.y;
        acc[m][nt][g * 4 + 2] = bv.z; acc[m][nt][g * 4 + 3] = bv.w;
      }
    }
  }

  // B-frag: B[k = lh*8 + j][n = ll]  -> row = point, contiguous 8 ushorts
  const unsigned short* bbase = actIn + (ntb * 32 + ll) * S + (lh << 3);
  const unsigned short* abase = Wsw + (size_t)mt0 * nks * 512 + l * 8;

  for (int ks = 0; ks < nks; ++ks) {
    bf16x8 B[NT];
#pragma unroll
    for (int nt = 0; nt < NT; ++nt)
      B[nt] = *(const bf16x8*)(bbase + nt * 32 * S + ks * 16);
#pragma unroll
    for (int m = 0; m < MT; ++m) {
      bf16x8 A = *(const bf16x8*)(abase + (m * nks + ks) * 512);
#pragma unroll
      for (int nt = 0; nt < NT; ++nt)
        acc[m][nt] = __builtin_amdgcn_mfma_f32_32x32x16_bf16(A, B[nt], acc[m][nt], 0, 0, 0);
    }
  }

  if (SYNC) __syncthreads();   // all B-reads done before any in-place store

#pragma unroll
  for (int m = 0; m < MT; ++m) {
#pragma unroll
    for (int g = 0; g < 4; ++g) {
      const int f0 = (mt0 + m) * 32 + g * 8 + (lh << 2);
      float4 gv;
      if (EP == 3) {
        float4 gg = *(const float4*)(gate + f0);
        gv.x = __builtin_amdgcn_rcpf(1.0f + __expf(-gg.x));
        gv.y = __builtin_amdgcn_rcpf(1.0f + __expf(-gg.y));
        gv.z = __builtin_amdgcn_rcpf(1.0f + __expf(-gg.z));
        gv.w = __builtin_amdgcn_rcpf(1.0f + __expf(-gg.w));
      }
#pragma unroll
      for (int nt = 0; nt < NT; ++nt) {
        const int pt = (ntb + nt) * 32 + ll;
        float v[4];
        v[0] = acc[m][nt][g * 4 + 0]; v[1] = acc[m][nt][g * 4 + 1];
        v[2] = acc[m][nt][g * 4 + 2]; v[3] = acc[m][nt][g * 4 + 3];
        if (EP == 1) {
#pragma unroll
          for (int r = 0; r < 4; ++r) v[r] = gelu_fast(v[r]);
        } else if (EP == 2) {
#pragma unroll
          for (int r = 0; r < 4; ++r) v[r] = fmaxf(v[r], 0.0f);
        } else if (EP == 3) {
          uint2 rv = *(const uint2*)(res + pt * S + f0);
          v[0] = fmaf(gv.x, v[0], bf2f((unsigned short)(rv.x & 0xffffu)));
          v[1] = fmaf(gv.y, v[1], bf2f((unsigned short)(rv.x >> 16)));
          v[2] = fmaf(gv.z, v[2], bf2f((unsigned short)(rv.y & 0xffffu)));
          v[3] = fmaf(gv.w, v[3], bf2f((unsigned short)(rv.y >> 16)));
        }
        uint2 pk;
        pk.x = pack2bf(v[0], v[1]);
        pk.y = pack2bf(v[2], v[3]);
        *(uint2*)(actOut + pt * S + f0) = pk;
      }
    }
  }
}

// stage a y-lerped patch: NCOL cols x NCH channels of fm at rows y0/y1
template<int NCOL, int NCH>
__device__ void stage_patch(const float* __restrict__ fm, int HW, int Wimg,
                            int base, int y0, int y1, float wy,
                            float* patch, int PS)
{
  const int items = NCOL * NCH;
  for (int e = threadIdx.x; e < items; e += NTH) {
    int ch = e / NCOL, col = e - ch * NCOL;
    int ca = min(base + col, Wimg - 1);
    const float* pp = fm + ch * HW;
    float v0 = pp[y0 * Wimg + ca];
    float v1 = pp[y1 * Wimg + ca];
    patch[col * PS + ch] = fmaf(wy, v1 - v0, v0);
  }
}

// x-lerp from patch into bf16 B-layout buffer
template<int PAIRS>
__device__ void xlerp_tile(const float* __restrict__ patch, int PS,
                           const int* pc, const float* wxA,
                           unsigned short* outBuf, int colOff)
{
  const int items = MP * PAIRS;
  for (int it = threadIdx.x; it < items; it += NTH) {
    int pr = it & (PAIRS - 1);
    int pt = it / PAIRS;
    int cc = pc[pt];
    float wx = wxA[pt];
    float2 a = *(const float2*)(patch + (cc & 0xff) * PS + pr * 2);
    float2 b = *(const float2*)(patch + (cc >> 8) * PS + pr * 2);
    float r0 = fmaf(wx, b.x - a.x, a.x);
    float r1 = fmaf(wx, b.y - a.y, a.y);
    *(unsigned*)(outBuf + pt * S + colOff + pr * 2) = pack2bf(r0, r1);
  }
}

// gather-based bilinear (warped sample only)
__device__ void gather_tile(const float* __restrict__ fm, int C, int HW,
    const short* offs, const float* wxA, const float* wyA,
    unsigned short* outBuf, int colOff)
{
  const int items = MP * (C >> 1);
  for (int it = threadIdx.x; it < items; it += NTH) {
    int i = it & (MP - 1);
    int c2 = it >> 6;
    int o00 = offs[0 * MP + i], o01 = offs[1 * MP + i];
    int o10 = offs[2 * MP + i], o11 = offs[3 * MP + i];
    float wx = wxA[i], wy = wyA[i];
    const float* p0 = fm + (c2 * 2) * HW;
    const float* p1 = p0 + HW;
    float a0 = p0[o00], a1 = p0[o01], a2 = p0[o10], a3 = p0[o11];
    float b0 = p1[o00], b1 = p1[o01], b2 = p1[o10], b3 = p1[o11];
    float ax0 = fmaf(wx, a1 - a0, a0), ax1 = fmaf(wx, a3 - a2, a2);
    float bx0 = fmaf(wx, b1 - b0, b0), bx1 = fmaf(wx, b3 - b2, b2);
    float r0 = fmaf(wy, ax1 - ax0, ax0);
    float r1 = fmaf(wy, bx1 - bx0, bx0);
    *(unsigned*)(outBuf + i * S + colOff + c2 * 2) = pack2bf(r0, r1);
  }
}

__global__ __launch_bounds__(256, 3)
void ifd_kernel(Params p)
{
  __shared__ __align__(16) unsigned short buf[MP * S];   // 37888 B
  __shared__ __align__(16) float patchA[10 * 130];        // 5200 B (f8, then f16)
  __shared__ __align__(16) float patchC[10 * 66];         // 2640 B
  __shared__ float wH3[128];
  __shared__ short offsW[4 * MP];
  __shared__ int pc8[MP], pc16[MP];
  __shared__ float w8x[MP], w16x[MP], wWx[MP], wWy[MP];
  __shared__ float caxA[MP], cayA[MP], gxA[MP], gyA[MP];
  __shared__ int uy8_0, uy8_1, uy16_0, uy16_1, ubase8, ubase16;
  __shared__ float uwy8, uwy16;

  const int blk = blockIdx.x;
  const int bb = blk / (HF * BPR);
  const int r = blk % (HF * BPR);
  const int y = r >> 3;
  const int xb = (r & (BPR - 1)) * MP;
  const int t = threadIdx.x;

  if (t >= 128 && t < 256) wH3[t - 128] = p.h3w[t - 128];
  if (t < MP) {
    const int i = t;
    const int x = xb + i;
    const float lim = 1.0f - 1e-6f;
    float gx = (x + 0.5f) * (2.0f / WF) - 1.0f;
    float gy = (y + 0.5f) * (2.0f / HF) - 1.0f;
    gx = fminf(fmaxf(gx, -lim), lim);
    gy = fminf(fmaxf(gy, -lim), lim);
    gxA[i] = gx; gyA[i] = gy;

    float gx0 = fminf(fmaxf((xb + 0.5f) * (2.0f / WF) - 1.0f, -lim), lim);
    int base8 = min(max((int)floorf((gx0 + 1.0f) * 32.0f - 0.5f), 0), W8 - 1);
    int base16 = min(max((int)floorf((gx0 + 1.0f) * 16.0f - 0.5f), 0), W16g - 1);

    int x0, x1, y0, y1; float wx, wy;
    bilin_setup(gx, W8, x0, x1, wx);
    bilin_setup(gy, H8, y0, y1, wy);
    pc8[i] = (x0 - base8) | ((x1 - base8) << 8);
    w8x[i] = wx;
    int o00 = y0 * W8 + x0, o01 = y0 * W8 + x1;
    int o10 = y1 * W8 + x0, o11 = y1 * W8 + x1;

    int a0, a1, b0i, b1i; float vx, vy;
    bilin_setup(gx, W16g, a0, a1, vx);
    bilin_setup(gy, H16g, b0i, b1i, vy);
    pc16[i] = (a0 - base16) | ((a1 - base16) << 8);
    w16x[i] = vx;

    if (i == 0) {
      uy8_0 = y0; uy8_1 = y1; uwy8 = wy;
      uy16_0 = b0i; uy16_1 = b1i; uwy16 = vy;
      ubase8 = base8; ubase16 = base16;
    }

    const float* cf = p.coarse + bb * 2 * HWs8;
    float c00 = cf[o00], c01 = cf[o01], c10 = cf[o10], c11 = cf[o11];
    float cx0 = fmaf(wx, c01 - c00, c00), cx1 = fmaf(wx, c11 - c10, c10);
    float cfx = fmaf(wy, cx1 - cx0, cx0);
    const float* cf2 = cf + HWs8;
    c00 = cf2[o00]; c01 = cf2[o01]; c10 = cf2[o10]; c11 = cf2[o11];
    cx0 = fmaf(wx, c01 - c00, c00); cx1 = fmaf(wx, c11 - c10, c10);
    float cfy = fmaf(wy, cx1 - cx0, cx0);
    float cax = cfx * 8.0f, cay = cfy * 8.0f;
    caxA[i] = cax; cayA[i] = cay;

    float wxn = gx + cax * (2.0f / WF);
    float wyn = gy + cay * (2.0f / HF);
    wxn = fminf(fmaxf(wxn, -lim), lim);
    wyn = fminf(fmaxf(wyn, -lim), lim);
    int u0, u1, v0, v1; float uw, vw;
    bilin_setup(wxn, W8, u0, u1, uw);
    bilin_setup(wyn, H8, v0, v1, vw);
    offsW[0 * MP + i] = (short)(v0 * W8 + u0);
    offsW[1 * MP + i] = (short)(v0 * W8 + u1);
    offsW[2 * MP + i] = (short)(v1 * W8 + u0);
    offsW[3 * MP + i] = (short)(v1 * W8 + u1);
    wWx[i] = uw; wWy[i] = vw;
  }
  __syncthreads();

  // stage f8 + ctx patches (coalesced, y-lerped)
  stage_patch<10, 128>(p.feat_s8 + bb * 128 * HWs8, HWs8, W8,
                       ubase8, uy8_0, uy8_1, uwy8, patchA, 130);
  stage_patch<10, 64>(p.ctx_s8 + bb * 64 * HWs8, HWs8, W8,
                      ubase8, uy8_0, uy8_1, uwy8, patchC, 66);
  __syncthreads();
  xlerp_tile<64>(patchA, 130, pc8, w8x, buf, 128);   // f8  -> cols [128:256)
  xlerp_tile<32>(patchC, 66, pc8, w8x, buf, 0);      // ctx -> cols [0:64)
  __syncthreads();

  // Wc: in [0:64) K=64 -> out [128:256), residual same cols (per-thread RAW ok)
  mfma_layer<1, 2, 3, false>(p.ws + OFF_WC, p.bc, buf, 64, buf + 128, p.g1, buf + 128);
  // overlap: stage f16 patch (patchA dead; its readers finished pre-barrier)
  stage_patch<6, 128>(p.feat_s16 + bb * 128 * HWs16, HWs16, W16g,
                      ubase16, uy16_0, uy16_1, uwy16, patchA, 130);
  __syncthreads();
  // W1: in [128:256) K=128 -> out [0:256)   (overlaps input -> SYNC)
  mfma_layer<2, 2, 1, true>(p.ws + OFF_W1, p.b1, buf + 128, 128, buf, nullptr, nullptr);
  __syncthreads();
  // W2: in [0:256) K=256 -> out [0:128)     (SYNC)
  mfma_layer<1, 2, 0, true>(p.ws + OFF_W2, p.b2, buf, 256, buf, nullptr, nullptr);
  // f16 x-lerp -> cols [128:256)  (past W2's internal barrier: all reads done)
  xlerp_tile<64>(patchA, 130, pc16, w16x, buf, 128);
  __syncthreads();
  // Wp: in [0:128) -> out [128:256), residual same cols
  mfma_layer<1, 2, 3, false>(p.ws + OFF_WP, p.bp, buf, 128, buf + 128, p.g2, buf + 128);
  __syncthreads();
  // W3: in [128:256) K=128 -> out [0:256)   (SYNC)
  mfma_layer<2, 2, 1, true>(p.ws + OFF_W3, p.b3, buf + 128, 128, buf, nullptr, nullptr);
  __syncthreads();
  // W4: in [0:256) K=256 -> out [0:128)     (SYNC); then f1_warped -> [128:256),
  // extras -> [256:288)  (past W4's internal barrier)
  mfma_layer<1, 2, 0, true>(p.ws + OFF_W4, p.b4, buf, 256, buf, nullptr, nullptr);
  gather_tile(p.feat1_s8 + bb * 128 * HWs8, 128, HWs8, offsW, wWx, wWy, buf, 128);
  for (int idx = t; idx < MP * 16; idx += NTH) {
    int row = idx >> 4, c = idx & 15;
    unsigned val = 0;
    if (c == 0) val = pack2bf(gxA[row], gyA[row]);
    else if (c == 1) val = pack2bf(caxA[row] * (1.0f / WF), cayA[row] * (1.0f / HF));
    *(unsigned*)(buf + row * S + 256 + c * 2) = val;
  }
  __syncthreads();
  // flow head, all in-place
  mfma_layer<2, 2, 2, true>(p.ws + OFF_H0, p.h0b, buf, 288, buf, nullptr, nullptr);
  __syncthreads();
  mfma_layer<1, 2, 2, true>(p.ws + OFF_H1, p.h1b, buf, 256, buf, nullptr, nullptr);
  __syncthreads();
  mfma_layer<1, 1, 2, true>(p.ws + OFF_H2, p.h2b, buf, 128, buf, nullptr, nullptr);
  __syncthreads();

  // final 64->2 + output (fp32), vectorized LDS reads + LDS weights
  if (t < 128) {
    int i = t & 63, comp = t >> 6;
    float acc = p.h3b[comp];
    const unsigned short* rowp = buf + i * S;
#pragma unroll
    for (int k8 = 0; k8 < 8; ++k8) {
      uint4 av = *(const uint4*)(rowp + k8 * 8);
      const float* wp = wH3 + k8 * 16 + comp;
      unsigned u0 = av.x, u1 = av.y, u2 = av.z, u3 = av.w;
      acc = fmaf(__builtin_bit_cast(float, u0 << 16),          wp[0], acc);
      acc = fmaf(__builtin_bit_cast(float, u0 & 0xffff0000u),  wp[2], acc);
      acc = fmaf(__builtin_bit_cast(float, u1 << 16),          wp[4], acc);
      acc = fmaf(__builtin_bit_cast(float, u1 & 0xffff0000u),  wp[6], acc);
      acc = fmaf(__builtin_bit_cast(float, u2 << 16),          wp[8], acc);
      acc = fmaf(__builtin_bit_cast(float, u2 & 0xffff0000u),  wp[10], acc);
      acc = fmaf(__builtin_bit_cast(float, u3 << 16),          wp[12], acc);
      acc = fmaf(__builtin_bit_cast(float, u3 & 0xffff0000u),  wp[14], acc);
    }
    float flow = (comp ? cayA[i] : caxA[i]) + acc * (comp ? (float)HF : (float)WF);
    p.out[((bb * 2 + comp) * HF + y) * WF + xb + i] = flow;
  }
}

extern "C" void kernel_launch(void* const* d_in, const int* in_sizes, int n_in,
                              void* d_out, int out_size, void* d_ws, size_t ws_size,
                              hipStream_t stream) {
  PrepParams pp;
  pp.W[0] = (const float*)d_in[6];   // Wc
  pp.W[1] = (const float*)d_in[9];   // W1
  pp.W[2] = (const float*)d_in[11];  // W2
  pp.W[3] = (const float*)d_in[13];  // Wp
  pp.W[4] = (const float*)d_in[16];  // W3
  pp.W[5] = (const float*)d_in[18];  // W4
  pp.W[6] = (const float*)d_in[20];  // hw0
  pp.W[7] = (const float*)d_in[22];  // hw1
  pp.W[8] = (const float*)d_in[24];  // hw2
  pp.ws = (unsigned short*)d_ws;
  hipLaunchKernelGGL(prep_kernel, dim3((SWZ_TOTAL + NTH - 1) / NTH), dim3(NTH), 0, stream, pp);

  Params p;
  p.feat_s8  = (const float*)d_in[1];
  p.feat1_s8 = (const float*)d_in[2];
  p.feat_s16 = (const float*)d_in[3];
  p.ctx_s8   = (const float*)d_in[4];
  p.coarse   = (const float*)d_in[5];
  p.bc  = (const float*)d_in[7];
  p.g1  = (const float*)d_in[8];
  p.b1  = (const float*)d_in[10];
  p.b2  = (const float*)d_in[12];
  p.bp  = (const float*)d_in[14];
  p.g2  = (const float*)d_in[15];
  p.b3  = (const float*)d_in[17];
  p.b4  = (const float*)d_in[19];
  p.h0b = (const float*)d_in[21];
  p.h1b = (const float*)d_in[23];
  p.h2b = (const float*)d_in[25];
  p.h3w = (const float*)d_in[26];
  p.h3b = (const float*)d_in[27];
  p.ws  = (const unsigned short*)d_ws;
  p.out = (float*)d_out;

  hipLaunchKernelGGL(ifd_kernel, dim3(NBLK), dim3(NTH), 0, stream, p);
}